// Round 1
// baseline (651.912 us; speedup 1.0000x reference)
//
#include <hip/hip_runtime.h>

#define NF 128
#define NH 64
#define NC 40
#define TF_PARTITIONABLE 1   // flip to 0 if mask mismatch (legacy jax threefry path)

__device__ __forceinline__ unsigned rotl32(unsigned v, int s) { return (v << s) | (v >> (32 - s)); }

// threefry2x32 with key (0,42) = jax.random.key(42); returns the 32 random bits
// JAX uses for flat element idx of a [100000,128] uniform draw.
__device__ __forceinline__ unsigned threefry_bits(unsigned idx) {
  const unsigned k0 = 0u, k1 = 42u;
  const unsigned k2x = 0u ^ 42u ^ 0x1BD11BDAu;
  unsigned x0, x1;
#if TF_PARTITIONABLE
  x0 = 0u; x1 = idx;              // (hi, lo) of 64-bit iota
#else
  const unsigned H = 6400000u;    // size/2
  if (idx < H) { x0 = idx; x1 = idx + H; } else { x0 = idx - H; x1 = idx; }
#endif
  x0 += k0; x1 += k1;
  x0 += x1; x1 = rotl32(x1, 13); x1 ^= x0;
  x0 += x1; x1 = rotl32(x1, 15); x1 ^= x0;
  x0 += x1; x1 = rotl32(x1, 26); x1 ^= x0;
  x0 += x1; x1 = rotl32(x1, 6);  x1 ^= x0;
  x0 += k1; x1 += k2x + 1u;
  x0 += x1; x1 = rotl32(x1, 17); x1 ^= x0;
  x0 += x1; x1 = rotl32(x1, 29); x1 ^= x0;
  x0 += x1; x1 = rotl32(x1, 16); x1 ^= x0;
  x0 += x1; x1 = rotl32(x1, 24); x1 ^= x0;
  x0 += k2x; x1 += k0 + 2u;
  x0 += x1; x1 = rotl32(x1, 13); x1 ^= x0;
  x0 += x1; x1 = rotl32(x1, 15); x1 ^= x0;
  x0 += x1; x1 = rotl32(x1, 26); x1 ^= x0;
  x0 += x1; x1 = rotl32(x1, 6);  x1 ^= x0;
  x0 += k0; x1 += k1 + 3u;
  x0 += x1; x1 = rotl32(x1, 17); x1 ^= x0;
  x0 += x1; x1 = rotl32(x1, 29); x1 ^= x0;
  x0 += x1; x1 = rotl32(x1, 16); x1 ^= x0;
  x0 += x1; x1 = rotl32(x1, 24); x1 ^= x0;
  x0 += k1; x1 += k2x + 4u;
  x0 += x1; x1 = rotl32(x1, 13); x1 ^= x0;
  x0 += x1; x1 = rotl32(x1, 15); x1 ^= x0;
  x0 += x1; x1 = rotl32(x1, 26); x1 ^= x0;
  x0 += x1; x1 = rotl32(x1, 6);  x1 ^= x0;
  x0 += k2x; x1 += k0 + 5u;
#if TF_PARTITIONABLE
  return x0 ^ x1;                 // 32-bit partitionable path: xor of both words
#else
  return (idx < 6400000u) ? x0 : x1;
#endif
}

__global__ void k_deg(const int* __restrict__ dst, int* __restrict__ deg, int nE) {
  int e = blockIdx.x * blockDim.x + threadIdx.x;
  if (e < nE) atomicAdd(&deg[dst[e]], 1);
}

__global__ void k_dis(const int* __restrict__ deg, float* __restrict__ dis, int n) {
  int i = blockIdx.x * blockDim.x + threadIdx.x;
  if (i < n) dis[i] = rsqrtf((float)(deg[i] + 1));   // +1 = self-loop; deg>=1 always
}

__global__ __launch_bounds__(1024) void k_scan(const int* __restrict__ cnt, int* __restrict__ rp, int n) {
  __shared__ int sums[1024];
  int t = threadIdx.x;
  const int chunk = 100;
  int lo = t * chunk;
  int hi = lo + chunk; if (hi > n) hi = n;
  int s = 0;
  if (lo < n) {
    const int4* c4 = (const int4*)(cnt + lo);
    int m4 = (hi - lo) >> 2;
    for (int i2 = 0; i2 < m4; ++i2) { int4 v = c4[i2]; s += v.x + v.y + v.z + v.w; }
    for (int i2 = lo + m4 * 4; i2 < hi; ++i2) s += cnt[i2];
  }
  sums[t] = s;
  __syncthreads();
  for (int off = 1; off < 1024; off <<= 1) {
    int v = (t >= off) ? sums[t - off] : 0;
    __syncthreads();
    sums[t] += v;
    __syncthreads();
  }
  int run = (t == 0) ? 0 : sums[t - 1];
  if (lo < n) {
    for (int i2 = lo; i2 < hi; ++i2) { rp[i2] = run; run += cnt[i2]; }
  }
  if (t == 1023) rp[n] = sums[1023];
}

__global__ void k_fill(const int* __restrict__ src, const int* __restrict__ dst,
                       const float* __restrict__ dis, const int* __restrict__ rp,
                       int* __restrict__ cur, int* __restrict__ csrc, float* __restrict__ cnorm, int nE) {
  int e = blockIdx.x * blockDim.x + threadIdx.x;
  if (e >= nE) return;
  int s = src[e], d = dst[e];
  int pos = rp[d] + atomicAdd(&cur[d], 1);
  csrc[pos] = s;
  cnorm[pos] = dis[s] * dis[d];
}

// xw = dropout(x) @ W1.  16 nodes/block; wave = 4 nodes x 16 float4 feature lanes.
__global__ __launch_bounds__(256) void k_xw(const float* __restrict__ x, const float* __restrict__ W1,
                                            float* __restrict__ xw, int n) {
  __shared__ float W1s[NF * NH];     // [k][j], 32 KB
  __shared__ float xs[16][132];      // padded (+4) rows -> conflict-free b128
  int t = threadIdx.x;
  for (int i = t; i < NF * NH / 4; i += 256) ((float4*)W1s)[i] = ((const float4*)W1)[i];
  int nodeBase = blockIdx.x * 16;
  {
    int ebase = nodeBase * NF + t * 8;   // flat element index (fits in int)
    const float4* xp = (const float4*)x;
    float4 a = xp[(ebase >> 2)];
    float4 b = xp[(ebase >> 2) + 1];
    float v[8] = {a.x, a.y, a.z, a.w, b.x, b.y, b.z, b.w};
    int nloc = t >> 4, kbase = (t & 15) * 8;
#pragma unroll
    for (int q = 0; q < 8; ++q) {
      unsigned idx = (unsigned)(ebase + q);
      bool keep = (threefry_bits(idx) & 0x80000000u) == 0u;   // u < 0.5
      xs[nloc][kbase + q] = keep ? v[q] * 2.0f : 0.0f;        // /(1-p) with p=0.5
    }
  }
  __syncthreads();
  int wv = t >> 6, lane = t & 63;
  int nsub = lane >> 4, jg = lane & 15;
  int nloc = wv * 4 + nsub;
  int i = nodeBase + nloc;
  float4 acc = {0.f, 0.f, 0.f, 0.f};
  const float4* W4 = (const float4*)W1s;
  const float4* xr = (const float4*)&xs[nloc][0];
#pragma unroll 4
  for (int k4 = 0; k4 < NF / 4; ++k4) {
    float4 xv = xr[k4];
#pragma unroll
    for (int kk = 0; kk < 4; ++kk) {
      float4 w = W4[(k4 * 4 + kk) * 16 + jg];
      float xk = (&xv.x)[kk];
      acc.x += xk * w.x; acc.y += xk * w.y; acc.z += xk * w.z; acc.w += xk * w.w;
    }
  }
  ((float4*)xw)[i * 16 + jg] = acc;
}

// h = relu( sum_in norm*xw[src] + dis^2*xw[i] + b1 ).  One wave per node, lane = feature.
__global__ __launch_bounds__(256) void k_agg1(const float* __restrict__ xw, const int* __restrict__ rp,
                                              const int* __restrict__ csrc, const float* __restrict__ cnorm,
                                              const float* __restrict__ dis, const float* __restrict__ b1,
                                              float* __restrict__ h, int n) {
  int i = blockIdx.x * 4 + (threadIdx.x >> 6);
  if (i >= n) return;
  int lane = threadIdx.x & 63;
  float di = dis[i];
  float acc = di * di * xw[i * NH + lane] + b1[lane];
  int lo = rp[i], hi = rp[i + 1];
  for (int e0 = lo; e0 < hi; e0 += 64) {
    int e = e0 + lane;
    int sv = 0; float wvv = 0.f;
    if (e < hi) { sv = csrc[e]; wvv = cnorm[e]; }
    int cnt = hi - e0; if (cnt > 64) cnt = 64;
    for (int tt = 0; tt < cnt; ++tt) {
      int s = __shfl(sv, tt);
      float w = __shfl(wvv, tt);
      acc += w * xw[s * NH + lane];
    }
  }
  h[i * NH + lane] = fmaxf(acc, 0.f);
}

// hw = h @ W2
__global__ __launch_bounds__(256) void k_hw(const float* __restrict__ h, const float* __restrict__ W2,
                                            float* __restrict__ hw, int n) {
  __shared__ float W2s[NH * NC];     // [k][j], 10 KB
  __shared__ float hs[16][68];       // padded rows
  int t = threadIdx.x;
  for (int i = t; i < NH * NC / 4; i += 256) ((float4*)W2s)[i] = ((const float4*)W2)[i];
  int nodeBase = blockIdx.x * 16;
  {
    const float4* hp = (const float4*)(h + nodeBase * NH);
    float4 v = hp[t];                       // 256 f4 = 16 nodes x 64 floats
    *(float4*)&hs[t >> 4][(t & 15) * 4] = v;
  }
  __syncthreads();
  int wv = t >> 6, lane = t & 63;
  int nsub = lane >> 4, jg = lane & 15;
  int nloc = wv * 4 + nsub;
  int i = nodeBase + nloc;
  if (jg < 10) {                             // 10 float4 groups cover 40 outputs
    float4 acc = {0.f, 0.f, 0.f, 0.f};
    const float4* xr = (const float4*)&hs[nloc][0];
#pragma unroll 4
    for (int k4 = 0; k4 < NH / 4; ++k4) {
      float4 xv = xr[k4];
#pragma unroll
      for (int kk = 0; kk < 4; ++kk) {
        float4 w = *(const float4*)&W2s[(k4 * 4 + kk) * NC + jg * 4];
        float xk = (&xv.x)[kk];
        acc.x += xk * w.x; acc.y += xk * w.y; acc.z += xk * w.z; acc.w += xk * w.w;
      }
    }
    *(float4*)(hw + i * NC + jg * 4) = acc;
  }
}

// out = sum_in norm*hw[src] + dis^2*hw[i] + b2.  One wave per node, lanes 0..39 = features.
__global__ __launch_bounds__(256) void k_agg2(const float* __restrict__ hw, const int* __restrict__ rp,
                                              const int* __restrict__ csrc, const float* __restrict__ cnorm,
                                              const float* __restrict__ dis, const float* __restrict__ b2,
                                              float* __restrict__ out, int n) {
  int i = blockIdx.x * 4 + (threadIdx.x >> 6);
  if (i >= n) return;
  int lane = threadIdx.x & 63;
  float di = dis[i];
  float acc = 0.f;
  if (lane < NC) acc = di * di * hw[i * NC + lane] + b2[lane];
  int lo = rp[i], hi = rp[i + 1];
  for (int e0 = lo; e0 < hi; e0 += 64) {
    int e = e0 + lane;
    int sv = 0; float wvv = 0.f;
    if (e < hi) { sv = csrc[e]; wvv = cnorm[e]; }
    int cnt = hi - e0; if (cnt > 64) cnt = 64;
    for (int tt = 0; tt < cnt; ++tt) {
      int s = __shfl(sv, tt);
      float w = __shfl(wvv, tt);
      if (lane < NC) acc += w * hw[s * NC + lane];
    }
  }
  if (lane < NC) out[i * NC + lane] = acc;
}

extern "C" void kernel_launch(void* const* d_in, const int* in_sizes, int n_in,
                              void* d_out, int out_size, void* d_ws, size_t ws_size,
                              hipStream_t stream) {
  const float* x  = (const float*)d_in[0];
  const int*   ei = (const int*)d_in[1];     // harness stages integer inputs as int32
  const float* W1 = (const float*)d_in[2];
  const float* b1 = (const float*)d_in[3];
  const float* W2 = (const float*)d_in[4];
  const float* b2 = (const float*)d_in[5];
  float* out = (float*)d_out;
  int n  = in_sizes[0] / NF;    // 100000
  int nE = in_sizes[1] / 2;     // 1600000
  const int* src = ei;
  const int* dst = ei + nE;

  char* ws = (char*)d_ws;
  int*   deg   = (int*)(ws + 0);           // 400000 B
  int*   cur   = (int*)(ws + 400000);      // 400000 B
  float* dis   = (float*)(ws + 800000);    // 400000 B
  int*   rp    = (int*)(ws + 1200000);     // 400128 B (n+1 ints, padded)
  int*   csrc  = (int*)(ws + 1600128);     // 6.4 MB
  float* cnorm = (float*)(ws + 8000128);   // 6.4 MB
  float* xw    = (float*)(ws + 14400128);  // 25.6 MB
  float* h     = (float*)(ws + 40000128);  // 25.6 MB  (total ~65.6 MB)
  float* hw    = xw;                       // xw dead after agg1; reuse for hw (16 MB)

  hipMemsetAsync(deg, 0, 800000, stream);  // deg + cur (adjacent)

  k_deg <<<(nE + 255) / 256, 256, 0, stream>>>(dst, deg, nE);
  k_dis <<<(n + 255) / 256, 256, 0, stream>>>(deg, dis, n);
  k_scan<<<1, 1024, 0, stream>>>(deg, rp, n);
  k_fill<<<(nE + 255) / 256, 256, 0, stream>>>(src, dst, dis, rp, cur, csrc, cnorm, nE);
  k_xw  <<<n / 16, 256, 0, stream>>>(x, W1, xw, n);
  k_agg1<<<(n + 3) / 4, 256, 0, stream>>>(xw, rp, csrc, cnorm, dis, b1, h, n);
  k_hw  <<<n / 16, 256, 0, stream>>>(h, W2, hw, n);
  k_agg2<<<(n + 3) / 4, 256, 0, stream>>>(hw, rp, csrc, cnorm, dis, b2, out, n);
}

// Round 2
// 527.256 us; speedup vs baseline: 1.2364x; 1.2364x over previous
//
#include <hip/hip_runtime.h>

#define NF 128
#define NH 64
#define NC 40
#define TF_PARTITIONABLE 1
#define SCAN_BE 1024   // elements per scan block (256 threads x 4)

__device__ __forceinline__ unsigned rotl32(unsigned v, int s) { return (v << s) | (v >> (32 - s)); }

// threefry2x32 with key (0,42); partitionable path: bits = x0^x1 of counter (0, idx).
__device__ __forceinline__ unsigned threefry_bits(unsigned idx) {
  const unsigned k0 = 0u, k1 = 42u;
  const unsigned k2x = 0u ^ 42u ^ 0x1BD11BDAu;
  unsigned x0, x1;
#if TF_PARTITIONABLE
  x0 = 0u; x1 = idx;
#else
  const unsigned H = 6400000u;
  if (idx < H) { x0 = idx; x1 = idx + H; } else { x0 = idx - H; x1 = idx; }
#endif
  x0 += k0; x1 += k1;
  x0 += x1; x1 = rotl32(x1, 13); x1 ^= x0;
  x0 += x1; x1 = rotl32(x1, 15); x1 ^= x0;
  x0 += x1; x1 = rotl32(x1, 26); x1 ^= x0;
  x0 += x1; x1 = rotl32(x1, 6);  x1 ^= x0;
  x0 += k1; x1 += k2x + 1u;
  x0 += x1; x1 = rotl32(x1, 17); x1 ^= x0;
  x0 += x1; x1 = rotl32(x1, 29); x1 ^= x0;
  x0 += x1; x1 = rotl32(x1, 16); x1 ^= x0;
  x0 += x1; x1 = rotl32(x1, 24); x1 ^= x0;
  x0 += k2x; x1 += k0 + 2u;
  x0 += x1; x1 = rotl32(x1, 13); x1 ^= x0;
  x0 += x1; x1 = rotl32(x1, 15); x1 ^= x0;
  x0 += x1; x1 = rotl32(x1, 26); x1 ^= x0;
  x0 += x1; x1 = rotl32(x1, 6);  x1 ^= x0;
  x0 += k0; x1 += k1 + 3u;
  x0 += x1; x1 = rotl32(x1, 17); x1 ^= x0;
  x0 += x1; x1 = rotl32(x1, 29); x1 ^= x0;
  x0 += x1; x1 = rotl32(x1, 16); x1 ^= x0;
  x0 += x1; x1 = rotl32(x1, 24); x1 ^= x0;
  x0 += k1; x1 += k2x + 4u;
  x0 += x1; x1 = rotl32(x1, 13); x1 ^= x0;
  x0 += x1; x1 = rotl32(x1, 15); x1 ^= x0;
  x0 += x1; x1 = rotl32(x1, 26); x1 ^= x0;
  x0 += x1; x1 = rotl32(x1, 6);  x1 ^= x0;
  x0 += k2x; x1 += k0 + 5u;
#if TF_PARTITIONABLE
  return x0 ^ x1;
#else
  return (idx < 6400000u) ? x0 : x1;
#endif
}

__global__ void k_deg(const int* __restrict__ dst, int* __restrict__ deg, int nE) {
  int e = blockIdx.x * blockDim.x + threadIdx.x;
  if (e < nE) atomicAdd(&deg[dst[e]], 1);
}

__global__ void k_dis(const int* __restrict__ deg, float* __restrict__ dis, int n) {
  int i = blockIdx.x * blockDim.x + threadIdx.x;
  if (i < n) dis[i] = rsqrtf((float)(deg[i] + 1));
}

// --- hierarchical scan: replaces the 137us single-block k_scan ---
__global__ __launch_bounds__(256) void k_scan1(const int* __restrict__ cnt, int* __restrict__ bsum, int n) {
  int t = threadIdx.x;
  int base = blockIdx.x * SCAN_BE + t * 4;
  int s = 0;
  if (base + 3 < n) { int4 v = *(const int4*)(cnt + base); s = v.x + v.y + v.z + v.w; }
  else { for (int q = 0; q < 4; ++q) if (base + q < n) s += cnt[base + q]; }
  for (int off = 32; off; off >>= 1) s += __shfl_down(s, off);
  __shared__ int wsum[4];
  if ((t & 63) == 0) wsum[t >> 6] = s;
  __syncthreads();
  if (t == 0) bsum[blockIdx.x] = wsum[0] + wsum[1] + wsum[2] + wsum[3];
}

__global__ __launch_bounds__(128) void k_scan2(const int* __restrict__ bsum, int* __restrict__ bpre,
                                               int* __restrict__ rp_total, int nb) {
  int t = threadIdx.x;
  int v = (t < nb) ? bsum[t] : 0;
  __shared__ int sh[128];
  sh[t] = v; __syncthreads();
  for (int off = 1; off < 128; off <<= 1) {
    int u = (t >= off) ? sh[t - off] : 0; __syncthreads();
    sh[t] += u; __syncthreads();
  }
  if (t < nb) bpre[t] = sh[t] - v;          // exclusive prefix
  if (t == 127) *rp_total = sh[127];        // rp[n]
}

__global__ __launch_bounds__(256) void k_scan3(const int* __restrict__ cnt, const int* __restrict__ bpre,
                                               int* __restrict__ rp, int n) {
  int t = threadIdx.x;
  int base = blockIdx.x * SCAN_BE + t * 4;
  int v[4] = {0, 0, 0, 0};
  if (base + 3 < n) { int4 c = *(const int4*)(cnt + base); v[0] = c.x; v[1] = c.y; v[2] = c.z; v[3] = c.w; }
  else { for (int q = 0; q < 4; ++q) if (base + q < n) v[q] = cnt[base + q]; }
  int ts = v[0] + v[1] + v[2] + v[3];
  __shared__ int sh[256];
  sh[t] = ts; __syncthreads();
  for (int off = 1; off < 256; off <<= 1) {
    int u = (t >= off) ? sh[t - off] : 0; __syncthreads();
    sh[t] += u; __syncthreads();
  }
  int run = bpre[blockIdx.x] + sh[t] - ts;  // block offset + exclusive within block
  for (int q = 0; q < 4; ++q) { if (base + q < n) rp[base + q] = run; run += v[q]; }
}

__global__ void k_fill(const int* __restrict__ src, const int* __restrict__ dst,
                       const float* __restrict__ dis, const int* __restrict__ rp,
                       int* __restrict__ cur, int* __restrict__ csrc, float* __restrict__ cnorm, int nE) {
  int e = blockIdx.x * blockDim.x + threadIdx.x;
  if (e >= nE) return;
  int s = src[e], d = dst[e];
  int pos = rp[d] + atomicAdd(&cur[d], 1);
  csrc[pos] = s;
  cnorm[pos] = dis[s] * dis[d];
}

// xw = dropout(x) @ W1.  16 nodes/block; wave = 4 nodes x 16 float4 feature lanes.
__global__ __launch_bounds__(256) void k_xw(const float* __restrict__ x, const float* __restrict__ W1,
                                            float* __restrict__ xw, int n) {
  __shared__ float W1s[NF * NH];
  __shared__ float xs[16][132];
  int t = threadIdx.x;
  for (int i = t; i < NF * NH / 4; i += 256) ((float4*)W1s)[i] = ((const float4*)W1)[i];
  int nodeBase = blockIdx.x * 16;
  {
    int ebase = nodeBase * NF + t * 8;
    const float4* xp = (const float4*)x;
    float4 a = xp[(ebase >> 2)];
    float4 b = xp[(ebase >> 2) + 1];
    float v[8] = {a.x, a.y, a.z, a.w, b.x, b.y, b.z, b.w};
    int nloc = t >> 4, kbase = (t & 15) * 8;
#pragma unroll
    for (int q = 0; q < 8; ++q) {
      unsigned idx = (unsigned)(ebase + q);
      bool keep = (threefry_bits(idx) & 0x80000000u) == 0u;
      xs[nloc][kbase + q] = keep ? v[q] * 2.0f : 0.0f;
    }
  }
  __syncthreads();
  int wv = t >> 6, lane = t & 63;
  int nsub = lane >> 4, jg = lane & 15;
  int nloc = wv * 4 + nsub;
  int i = nodeBase + nloc;
  float4 acc = {0.f, 0.f, 0.f, 0.f};
  const float4* W4 = (const float4*)W1s;
  const float4* xr = (const float4*)&xs[nloc][0];
#pragma unroll 4
  for (int k4 = 0; k4 < NF / 4; ++k4) {
    float4 xv = xr[k4];
#pragma unroll
    for (int kk = 0; kk < 4; ++kk) {
      float4 w = W4[(k4 * 4 + kk) * 16 + jg];
      float xk = (&xv.x)[kk];
      acc.x += xk * w.x; acc.y += xk * w.y; acc.z += xk * w.z; acc.w += xk * w.w;
    }
  }
  ((float4*)xw)[i * 16 + jg] = acc;
}

// h = relu( sum_in norm*xw[src] + dis^2*xw[i] + b1 ).  One wave per node, lane = feature.
__global__ __launch_bounds__(256) void k_agg1(const float* __restrict__ xw, const int* __restrict__ rp,
                                              const int* __restrict__ csrc, const float* __restrict__ cnorm,
                                              const float* __restrict__ dis, const float* __restrict__ b1,
                                              float* __restrict__ h, int n) {
  int i = blockIdx.x * 4 + (threadIdx.x >> 6);
  if (i >= n) return;
  int lane = threadIdx.x & 63;
  float di = dis[i];
  float acc = di * di * xw[i * NH + lane] + b1[lane];
  int lo = rp[i], hi = rp[i + 1];
  for (int e0 = lo; e0 < hi; e0 += 64) {
    int e = e0 + lane;
    int sv = 0; float wvv = 0.f;
    if (e < hi) { sv = csrc[e]; wvv = cnorm[e]; }
    int cnt = hi - e0; if (cnt > 64) cnt = 64;
    for (int tt = 0; tt < cnt; ++tt) {
      int s = __shfl(sv, tt);
      float w = __shfl(wvv, tt);
      acc += w * xw[s * NH + lane];
    }
  }
  h[i * NH + lane] = fmaxf(acc, 0.f);
}

// hw = h @ W2
__global__ __launch_bounds__(256) void k_hw(const float* __restrict__ h, const float* __restrict__ W2,
                                            float* __restrict__ hw, int n) {
  __shared__ float W2s[NH * NC];
  __shared__ float hs[16][68];
  int t = threadIdx.x;
  for (int i = t; i < NH * NC / 4; i += 256) ((float4*)W2s)[i] = ((const float4*)W2)[i];
  int nodeBase = blockIdx.x * 16;
  {
    const float4* hp = (const float4*)(h + nodeBase * NH);
    float4 v = hp[t];
    *(float4*)&hs[t >> 4][(t & 15) * 4] = v;
  }
  __syncthreads();
  int wv = t >> 6, lane = t & 63;
  int nsub = lane >> 4, jg = lane & 15;
  int nloc = wv * 4 + nsub;
  int i = nodeBase + nloc;
  if (jg < 10) {
    float4 acc = {0.f, 0.f, 0.f, 0.f};
    const float4* xr = (const float4*)&hs[nloc][0];
#pragma unroll 4
    for (int k4 = 0; k4 < NH / 4; ++k4) {
      float4 xv = xr[k4];
#pragma unroll
      for (int kk = 0; kk < 4; ++kk) {
        float4 w = *(const float4*)&W2s[(k4 * 4 + kk) * NC + jg * 4];
        float xk = (&xv.x)[kk];
        acc.x += xk * w.x; acc.y += xk * w.y; acc.z += xk * w.z; acc.w += xk * w.w;
      }
    }
    *(float4*)(hw + i * NC + jg * 4) = acc;
  }
}

// out = sum_in norm*hw[src] + dis^2*hw[i] + b2.  One wave per node, lanes 0..39 = features.
__global__ __launch_bounds__(256) void k_agg2(const float* __restrict__ hw, const int* __restrict__ rp,
                                              const int* __restrict__ csrc, const float* __restrict__ cnorm,
                                              const float* __restrict__ dis, const float* __restrict__ b2,
                                              float* __restrict__ out, int n) {
  int i = blockIdx.x * 4 + (threadIdx.x >> 6);
  if (i >= n) return;
  int lane = threadIdx.x & 63;
  float di = dis[i];
  float acc = 0.f;
  if (lane < NC) acc = di * di * hw[i * NC + lane] + b2[lane];
  int lo = rp[i], hi = rp[i + 1];
  for (int e0 = lo; e0 < hi; e0 += 64) {
    int e = e0 + lane;
    int sv = 0; float wvv = 0.f;
    if (e < hi) { sv = csrc[e]; wvv = cnorm[e]; }
    int cnt = hi - e0; if (cnt > 64) cnt = 64;
    for (int tt = 0; tt < cnt; ++tt) {
      int s = __shfl(sv, tt);
      float w = __shfl(wvv, tt);
      if (lane < NC) acc += w * hw[s * NC + lane];
    }
  }
  if (lane < NC) out[i * NC + lane] = acc;
}

extern "C" void kernel_launch(void* const* d_in, const int* in_sizes, int n_in,
                              void* d_out, int out_size, void* d_ws, size_t ws_size,
                              hipStream_t stream) {
  const float* x  = (const float*)d_in[0];
  const int*   ei = (const int*)d_in[1];
  const float* W1 = (const float*)d_in[2];
  const float* b1 = (const float*)d_in[3];
  const float* W2 = (const float*)d_in[4];
  const float* b2 = (const float*)d_in[5];
  float* out = (float*)d_out;
  int n  = in_sizes[0] / NF;    // 100000
  int nE = in_sizes[1] / 2;     // 1600000
  const int* src = ei;
  const int* dst = ei + nE;

  char* ws = (char*)d_ws;
  int*   deg   = (int*)(ws + 0);           // 400000 B
  int*   cur   = (int*)(ws + 400000);      // 400000 B
  float* dis   = (float*)(ws + 800000);    // 400000 B
  int*   rp    = (int*)(ws + 1200000);     // n+1 ints (+pad)
  int*   bsum  = (int*)(ws + 1600640);     // 128 ints
  int*   bpre  = (int*)(ws + 1601152);     // 128 ints
  int*   csrc  = (int*)(ws + 1601664);     // 6.4 MB
  float* cnorm = (float*)(ws + 8001664);   // 6.4 MB
  float* xw    = (float*)(ws + 14401664);  // 25.6 MB
  float* h     = (float*)(ws + 40001664);  // 25.6 MB
  float* hw    = xw;                       // reuse: xw dead after agg1

  hipMemsetAsync(deg, 0, 800000, stream);  // deg + cur

  int nbScan = (n + SCAN_BE - 1) / SCAN_BE;   // 98
  k_deg  <<<(nE + 255) / 256, 256, 0, stream>>>(dst, deg, nE);
  k_dis  <<<(n + 255) / 256, 256, 0, stream>>>(deg, dis, n);
  k_scan1<<<nbScan, 256, 0, stream>>>(deg, bsum, n);
  k_scan2<<<1, 128, 0, stream>>>(bsum, bpre, rp + n, nbScan);
  k_scan3<<<nbScan, 256, 0, stream>>>(deg, bpre, rp, n);
  k_fill <<<(nE + 255) / 256, 256, 0, stream>>>(src, dst, dis, rp, cur, csrc, cnorm, nE);
  k_xw   <<<n / 16, 256, 0, stream>>>(x, W1, xw, n);
  k_agg1 <<<(n + 3) / 4, 256, 0, stream>>>(xw, rp, csrc, cnorm, dis, b1, h, n);
  k_hw   <<<n / 16, 256, 0, stream>>>(h, W2, hw, n);
  k_agg2 <<<(n + 3) / 4, 256, 0, stream>>>(hw, rp, csrc, cnorm, dis, b2, out, n);
}

// Round 3
// 453.179 us; speedup vs baseline: 1.4385x; 1.1635x over previous
//
#include <hip/hip_runtime.h>

#define NF 128
#define NH 64
#define NC 40
#define SCAN_BE 1024

__device__ __forceinline__ unsigned rotl32(unsigned v, int s) { return (v << s) | (v >> (32 - s)); }

// threefry2x32, key(0,42), partitionable path: bits = x0^x1 of counter (0, idx).
__device__ __forceinline__ unsigned threefry_bits(unsigned idx) {
  const unsigned k0 = 0u, k1 = 42u;
  const unsigned k2x = 0u ^ 42u ^ 0x1BD11BDAu;
  unsigned x0 = 0u, x1 = idx;
  x0 += k0; x1 += k1;
  x0 += x1; x1 = rotl32(x1, 13); x1 ^= x0;
  x0 += x1; x1 = rotl32(x1, 15); x1 ^= x0;
  x0 += x1; x1 = rotl32(x1, 26); x1 ^= x0;
  x0 += x1; x1 = rotl32(x1, 6);  x1 ^= x0;
  x0 += k1; x1 += k2x + 1u;
  x0 += x1; x1 = rotl32(x1, 17); x1 ^= x0;
  x0 += x1; x1 = rotl32(x1, 29); x1 ^= x0;
  x0 += x1; x1 = rotl32(x1, 16); x1 ^= x0;
  x0 += x1; x1 = rotl32(x1, 24); x1 ^= x0;
  x0 += k2x; x1 += k0 + 2u;
  x0 += x1; x1 = rotl32(x1, 13); x1 ^= x0;
  x0 += x1; x1 = rotl32(x1, 15); x1 ^= x0;
  x0 += x1; x1 = rotl32(x1, 26); x1 ^= x0;
  x0 += x1; x1 = rotl32(x1, 6);  x1 ^= x0;
  x0 += k0; x1 += k1 + 3u;
  x0 += x1; x1 = rotl32(x1, 17); x1 ^= x0;
  x0 += x1; x1 = rotl32(x1, 29); x1 ^= x0;
  x0 += x1; x1 = rotl32(x1, 16); x1 ^= x0;
  x0 += x1; x1 = rotl32(x1, 24); x1 ^= x0;
  x0 += k1; x1 += k2x + 4u;
  x0 += x1; x1 = rotl32(x1, 13); x1 ^= x0;
  x0 += x1; x1 = rotl32(x1, 15); x1 ^= x0;
  x0 += x1; x1 = rotl32(x1, 26); x1 ^= x0;
  x0 += x1; x1 = rotl32(x1, 6);  x1 ^= x0;
  x0 += k2x; x1 += k0 + 5u;
  return x0 ^ x1;
}

__global__ void k_deg(const int* __restrict__ dst, int* __restrict__ deg, int nE) {
  int e = blockIdx.x * blockDim.x + threadIdx.x;
  if (e < nE) atomicAdd(&deg[dst[e]], 1);
}

__global__ void k_dis(const int* __restrict__ deg, float* __restrict__ dis, int n) {
  int i = blockIdx.x * blockDim.x + threadIdx.x;
  if (i < n) dis[i] = rsqrtf((float)(deg[i] + 1));
}

__global__ __launch_bounds__(256) void k_scan1(const int* __restrict__ cnt, int* __restrict__ bsum, int n) {
  int t = threadIdx.x;
  int base = blockIdx.x * SCAN_BE + t * 4;
  int s = 0;
  if (base + 3 < n) { int4 v = *(const int4*)(cnt + base); s = v.x + v.y + v.z + v.w; }
  else { for (int q = 0; q < 4; ++q) if (base + q < n) s += cnt[base + q]; }
  for (int off = 32; off; off >>= 1) s += __shfl_down(s, off);
  __shared__ int wsum[4];
  if ((t & 63) == 0) wsum[t >> 6] = s;
  __syncthreads();
  if (t == 0) bsum[blockIdx.x] = wsum[0] + wsum[1] + wsum[2] + wsum[3];
}

__global__ __launch_bounds__(128) void k_scan2(const int* __restrict__ bsum, int* __restrict__ bpre,
                                               int* __restrict__ rp_total, int nb) {
  int t = threadIdx.x;
  int v = (t < nb) ? bsum[t] : 0;
  __shared__ int sh[128];
  sh[t] = v; __syncthreads();
  for (int off = 1; off < 128; off <<= 1) {
    int u = (t >= off) ? sh[t - off] : 0; __syncthreads();
    sh[t] += u; __syncthreads();
  }
  if (t < nb) bpre[t] = sh[t] - v;
  if (t == 127) *rp_total = sh[127];
}

__global__ __launch_bounds__(256) void k_scan3(const int* __restrict__ cnt, const int* __restrict__ bpre,
                                               int* __restrict__ rp, int n) {
  int t = threadIdx.x;
  int base = blockIdx.x * SCAN_BE + t * 4;
  int v[4] = {0, 0, 0, 0};
  if (base + 3 < n) { int4 c = *(const int4*)(cnt + base); v[0] = c.x; v[1] = c.y; v[2] = c.z; v[3] = c.w; }
  else { for (int q = 0; q < 4; ++q) if (base + q < n) v[q] = cnt[base + q]; }
  int ts = v[0] + v[1] + v[2] + v[3];
  __shared__ int sh[256];
  sh[t] = ts; __syncthreads();
  for (int off = 1; off < 256; off <<= 1) {
    int u = (t >= off) ? sh[t - off] : 0; __syncthreads();
    sh[t] += u; __syncthreads();
  }
  int run = bpre[blockIdx.x] + sh[t] - ts;
  for (int q = 0; q < 4; ++q) { if (base + q < n) rp[base + q] = run; run += v[q]; }
}

// CSR fill: src only (norm factorized out entirely).
__global__ void k_fill(const int* __restrict__ src, const int* __restrict__ dst,
                       const int* __restrict__ rp, int* __restrict__ cur,
                       int* __restrict__ csrc, int nE) {
  int e = blockIdx.x * blockDim.x + threadIdx.x;
  if (e >= nE) return;
  int d = dst[e];
  int pos = rp[d] + atomicAdd(&cur[d], 1);
  csrc[pos] = src[e];
}

// y1 = dis[i] * (dropout(x) @ W1).  16 nodes/block.
__global__ __launch_bounds__(256) void k_xw(const float* __restrict__ x, const float* __restrict__ W1,
                                            const float* __restrict__ dis, float* __restrict__ y1, int n) {
  __shared__ float W1s[NF * NH];
  __shared__ float xs[16][132];
  int t = threadIdx.x;
  for (int i = t; i < NF * NH / 4; i += 256) ((float4*)W1s)[i] = ((const float4*)W1)[i];
  int nodeBase = blockIdx.x * 16;
  {
    int ebase = nodeBase * NF + t * 8;
    const float4* xp = (const float4*)x;
    float4 a = xp[(ebase >> 2)];
    float4 b = xp[(ebase >> 2) + 1];
    float v[8] = {a.x, a.y, a.z, a.w, b.x, b.y, b.z, b.w};
    int nloc = t >> 4, kbase = (t & 15) * 8;
#pragma unroll
    for (int q = 0; q < 8; ++q) {
      unsigned idx = (unsigned)(ebase + q);
      bool keep = (threefry_bits(idx) & 0x80000000u) == 0u;
      xs[nloc][kbase + q] = keep ? v[q] * 2.0f : 0.0f;
    }
  }
  __syncthreads();
  int wv = t >> 6, lane = t & 63;
  int nsub = lane >> 4, jg = lane & 15;
  int nloc = wv * 4 + nsub;
  int i = nodeBase + nloc;
  float4 acc = {0.f, 0.f, 0.f, 0.f};
  const float4* W4 = (const float4*)W1s;
  const float4* xr = (const float4*)&xs[nloc][0];
#pragma unroll 4
  for (int k4 = 0; k4 < NF / 4; ++k4) {
    float4 xv = xr[k4];
#pragma unroll
    for (int kk = 0; kk < 4; ++kk) {
      float4 w = W4[(k4 * 4 + kk) * 16 + jg];
      float xk = (&xv.x)[kk];
      acc.x += xk * w.x; acc.y += xk * w.y; acc.z += xk * w.z; acc.w += xk * w.w;
    }
  }
  float di = dis[i];
  acc.x *= di; acc.y *= di; acc.z *= di; acc.w *= di;
  ((float4*)y1)[i * 16 + jg] = acc;
}

// h = relu( dis[i] * (sum_{in} y1[src] + y1[i]) + b1 ).  Wave/node, lane=feature.
// 8-way unrolled gather: 8 independent loads in flight per wave.
__global__ __launch_bounds__(256) void k_agg1(const float* __restrict__ y1, const int* __restrict__ rp,
                                              const int* __restrict__ csrc, const float* __restrict__ dis,
                                              const float* __restrict__ b1, float* __restrict__ h, int n) {
  int i = blockIdx.x * 4 + (threadIdx.x >> 6);
  if (i >= n) return;
  int lane = threadIdx.x & 63;
  float acc = y1[i * NH + lane];   // self-loop
  float a0 = 0.f, a1 = 0.f, a2 = 0.f, a3 = 0.f, a4 = 0.f, a5 = 0.f, a6 = 0.f, a7 = 0.f;
  int lo = rp[i], hi = rp[i + 1];
  for (int e0 = lo; e0 < hi; e0 += 64) {
    int e = e0 + lane;
    int sv = (e < hi) ? csrc[e] : 0;
    int cnt = hi - e0; if (cnt > 64) cnt = 64;
    int tt = 0;
    for (; tt + 8 <= cnt; tt += 8) {
      int s0 = __shfl(sv, tt + 0), s1 = __shfl(sv, tt + 1), s2 = __shfl(sv, tt + 2), s3 = __shfl(sv, tt + 3);
      int s4 = __shfl(sv, tt + 4), s5 = __shfl(sv, tt + 5), s6 = __shfl(sv, tt + 6), s7 = __shfl(sv, tt + 7);
      float v0 = y1[s0 * NH + lane], v1 = y1[s1 * NH + lane], v2 = y1[s2 * NH + lane], v3 = y1[s3 * NH + lane];
      float v4 = y1[s4 * NH + lane], v5 = y1[s5 * NH + lane], v6 = y1[s6 * NH + lane], v7 = y1[s7 * NH + lane];
      a0 += v0; a1 += v1; a2 += v2; a3 += v3; a4 += v4; a5 += v5; a6 += v6; a7 += v7;
    }
    for (; tt + 4 <= cnt; tt += 4) {
      int s0 = __shfl(sv, tt + 0), s1 = __shfl(sv, tt + 1), s2 = __shfl(sv, tt + 2), s3 = __shfl(sv, tt + 3);
      float v0 = y1[s0 * NH + lane], v1 = y1[s1 * NH + lane], v2 = y1[s2 * NH + lane], v3 = y1[s3 * NH + lane];
      a0 += v0; a1 += v1; a2 += v2; a3 += v3;
    }
    for (; tt < cnt; ++tt) {
      int s = __shfl(sv, tt);
      acc += y1[s * NH + lane];
    }
  }
  acc += ((a0 + a1) + (a2 + a3)) + ((a4 + a5) + (a6 + a7));
  h[i * NH + lane] = fmaxf(fmaf(dis[i], acc, b1[lane]), 0.f);
}

// y2 = dis[i] * (h @ W2)   (b2 deferred to agg2)
__global__ __launch_bounds__(256) void k_hw(const float* __restrict__ h, const float* __restrict__ W2,
                                            const float* __restrict__ dis, float* __restrict__ y2, int n) {
  __shared__ float W2s[NH * NC];
  __shared__ float hs[16][68];
  int t = threadIdx.x;
  for (int i = t; i < NH * NC / 4; i += 256) ((float4*)W2s)[i] = ((const float4*)W2)[i];
  int nodeBase = blockIdx.x * 16;
  {
    const float4* hp = (const float4*)(h + nodeBase * NH);
    float4 v = hp[t];
    *(float4*)&hs[t >> 4][(t & 15) * 4] = v;
  }
  __syncthreads();
  int wv = t >> 6, lane = t & 63;
  int nsub = lane >> 4, jg = lane & 15;
  int nloc = wv * 4 + nsub;
  int i = nodeBase + nloc;
  if (jg < 10) {
    float4 acc = {0.f, 0.f, 0.f, 0.f};
    const float4* xr = (const float4*)&hs[nloc][0];
#pragma unroll 4
    for (int k4 = 0; k4 < NH / 4; ++k4) {
      float4 xv = xr[k4];
#pragma unroll
      for (int kk = 0; kk < 4; ++kk) {
        float4 w = *(const float4*)&W2s[(k4 * 4 + kk) * NC + jg * 4];
        float xk = (&xv.x)[kk];
        acc.x += xk * w.x; acc.y += xk * w.y; acc.z += xk * w.z; acc.w += xk * w.w;
      }
    }
    float di = dis[i];
    acc.x *= di; acc.y *= di; acc.z *= di; acc.w *= di;
    *(float4*)(y2 + i * NC + jg * 4) = acc;
  }
}

// out = dis[i] * (sum_{in} y2[src] + y2[i]) + b2.  Lanes 0..39 = features.
__global__ __launch_bounds__(256) void k_agg2(const float* __restrict__ y2, const int* __restrict__ rp,
                                              const int* __restrict__ csrc, const float* __restrict__ dis,
                                              const float* __restrict__ b2, float* __restrict__ out, int n) {
  int i = blockIdx.x * 4 + (threadIdx.x >> 6);
  if (i >= n) return;
  int lane = threadIdx.x & 63;
  bool act = lane < NC;
  float acc = act ? y2[i * NC + lane] : 0.f;   // self-loop
  float a0 = 0.f, a1 = 0.f, a2 = 0.f, a3 = 0.f, a4 = 0.f, a5 = 0.f, a6 = 0.f, a7 = 0.f;
  int lo = rp[i], hi = rp[i + 1];
  for (int e0 = lo; e0 < hi; e0 += 64) {
    int e = e0 + lane;
    int sv = (e < hi) ? csrc[e] : 0;
    int cnt = hi - e0; if (cnt > 64) cnt = 64;
    int tt = 0;
    for (; tt + 8 <= cnt; tt += 8) {
      int s0 = __shfl(sv, tt + 0), s1 = __shfl(sv, tt + 1), s2 = __shfl(sv, tt + 2), s3 = __shfl(sv, tt + 3);
      int s4 = __shfl(sv, tt + 4), s5 = __shfl(sv, tt + 5), s6 = __shfl(sv, tt + 6), s7 = __shfl(sv, tt + 7);
      if (act) {
        float v0 = y2[s0 * NC + lane], v1 = y2[s1 * NC + lane], v2 = y2[s2 * NC + lane], v3 = y2[s3 * NC + lane];
        float v4 = y2[s4 * NC + lane], v5 = y2[s5 * NC + lane], v6 = y2[s6 * NC + lane], v7 = y2[s7 * NC + lane];
        a0 += v0; a1 += v1; a2 += v2; a3 += v3; a4 += v4; a5 += v5; a6 += v6; a7 += v7;
      }
    }
    for (; tt + 4 <= cnt; tt += 4) {
      int s0 = __shfl(sv, tt + 0), s1 = __shfl(sv, tt + 1), s2 = __shfl(sv, tt + 2), s3 = __shfl(sv, tt + 3);
      if (act) {
        float v0 = y2[s0 * NC + lane], v1 = y2[s1 * NC + lane], v2 = y2[s2 * NC + lane], v3 = y2[s3 * NC + lane];
        a0 += v0; a1 += v1; a2 += v2; a3 += v3;
      }
    }
    for (; tt < cnt; ++tt) {
      int s = __shfl(sv, tt);
      if (act) acc += y2[s * NC + lane];
    }
  }
  if (act) {
    acc += ((a0 + a1) + (a2 + a3)) + ((a4 + a5) + (a6 + a7));
    out[i * NC + lane] = fmaf(dis[i], acc, b2[lane]);
  }
}

extern "C" void kernel_launch(void* const* d_in, const int* in_sizes, int n_in,
                              void* d_out, int out_size, void* d_ws, size_t ws_size,
                              hipStream_t stream) {
  const float* x  = (const float*)d_in[0];
  const int*   ei = (const int*)d_in[1];
  const float* W1 = (const float*)d_in[2];
  const float* b1 = (const float*)d_in[3];
  const float* W2 = (const float*)d_in[4];
  const float* b2 = (const float*)d_in[5];
  float* out = (float*)d_out;
  int n  = in_sizes[0] / NF;    // 100000
  int nE = in_sizes[1] / 2;     // 1600000
  const int* src = ei;
  const int* dst = ei + nE;

  char* ws = (char*)d_ws;
  int*   deg  = (int*)(ws + 0);
  int*   cur  = (int*)(ws + 400000);
  float* dis  = (float*)(ws + 800000);
  int*   rp   = (int*)(ws + 1200000);      // n+1 ints
  int*   bsum = (int*)(ws + 1600640);
  int*   bpre = (int*)(ws + 1601152);
  int*   csrc = (int*)(ws + 1601664);      // 6.4 MB
  float* y1   = (float*)(ws + 8001664);    // 25.6 MB
  float* h    = (float*)(ws + 33601664);   // 25.6 MB
  float* y2   = y1;                        // reuse: y1 dead after agg1 (16 MB)

  hipMemsetAsync(deg, 0, 800000, stream);  // deg + cur

  int nbScan = (n + SCAN_BE - 1) / SCAN_BE;
  k_deg  <<<(nE + 255) / 256, 256, 0, stream>>>(dst, deg, nE);
  k_dis  <<<(n + 255) / 256, 256, 0, stream>>>(deg, dis, n);
  k_scan1<<<nbScan, 256, 0, stream>>>(deg, bsum, n);
  k_scan2<<<1, 128, 0, stream>>>(bsum, bpre, rp + n, nbScan);
  k_scan3<<<nbScan, 256, 0, stream>>>(deg, bpre, rp, n);
  k_fill <<<(nE + 255) / 256, 256, 0, stream>>>(src, dst, rp, cur, csrc, nE);
  k_xw   <<<n / 16, 256, 0, stream>>>(x, W1, dis, y1, n);
  k_agg1 <<<(n + 3) / 4, 256, 0, stream>>>(y1, rp, csrc, dis, b1, h, n);
  k_hw   <<<n / 16, 256, 0, stream>>>(h, W2, dis, y2, n);
  k_agg2 <<<(n + 3) / 4, 256, 0, stream>>>(y2, rp, csrc, dis, b2, out, n);
}

// Round 4
// 338.498 us; speedup vs baseline: 1.9259x; 1.3388x over previous
//
#include <hip/hip_runtime.h>

#define NF 128
#define NH 64
#define NC 40
#define BSHIFT 10                 // bucket = dst >> 10  (1024 nodes/bucket)
#define NB 98                     // ceil(100000 / 1024)
#define BIN_T 8192                // edges per k_bin block

__device__ __forceinline__ unsigned rotl32(unsigned v, int s) { return (v << s) | (v >> (32 - s)); }

// threefry2x32, key(0,42), partitionable path: bits = x0^x1 of counter (0, idx).
__device__ __forceinline__ unsigned threefry_bits(unsigned idx) {
  const unsigned k0 = 0u, k1 = 42u;
  const unsigned k2x = 0u ^ 42u ^ 0x1BD11BDAu;
  unsigned x0 = 0u, x1 = idx;
  x0 += k0; x1 += k1;
  x0 += x1; x1 = rotl32(x1, 13); x1 ^= x0;
  x0 += x1; x1 = rotl32(x1, 15); x1 ^= x0;
  x0 += x1; x1 = rotl32(x1, 26); x1 ^= x0;
  x0 += x1; x1 = rotl32(x1, 6);  x1 ^= x0;
  x0 += k1; x1 += k2x + 1u;
  x0 += x1; x1 = rotl32(x1, 17); x1 ^= x0;
  x0 += x1; x1 = rotl32(x1, 29); x1 ^= x0;
  x0 += x1; x1 = rotl32(x1, 16); x1 ^= x0;
  x0 += x1; x1 = rotl32(x1, 24); x1 ^= x0;
  x0 += k2x; x1 += k0 + 2u;
  x0 += x1; x1 = rotl32(x1, 13); x1 ^= x0;
  x0 += x1; x1 = rotl32(x1, 15); x1 ^= x0;
  x0 += x1; x1 = rotl32(x1, 26); x1 ^= x0;
  x0 += x1; x1 = rotl32(x1, 6);  x1 ^= x0;
  x0 += k0; x1 += k1 + 3u;
  x0 += x1; x1 = rotl32(x1, 17); x1 ^= x0;
  x0 += x1; x1 = rotl32(x1, 29); x1 ^= x0;
  x0 += x1; x1 = rotl32(x1, 16); x1 ^= x0;
  x0 += x1; x1 = rotl32(x1, 24); x1 ^= x0;
  x0 += k1; x1 += k2x + 4u;
  x0 += x1; x1 = rotl32(x1, 13); x1 ^= x0;
  x0 += x1; x1 = rotl32(x1, 15); x1 ^= x0;
  x0 += x1; x1 = rotl32(x1, 26); x1 ^= x0;
  x0 += x1; x1 = rotl32(x1, 6);  x1 ^= x0;
  x0 += k2x; x1 += k0 + 5u;
  return x0 ^ x1;
}

// Global bucket histogram (LDS-staged).
__global__ __launch_bounds__(256) void k_bhist(const int* __restrict__ dst, int* __restrict__ bcnt, int nE) {
  __shared__ int h[NB];
  int t = threadIdx.x;
  if (t < NB) h[t] = 0;
  __syncthreads();
  int stride = gridDim.x * 256;
  for (int e = blockIdx.x * 256 + t; e < nE; e += stride)
    atomicAdd(&h[dst[e] >> BSHIFT], 1);
  __syncthreads();
  if (t < NB && h[t]) atomicAdd(&bcnt[t], h[t]);
}

// Scan 98 bucket counts -> bucket bases (= CSR bases); seed scatter cursors; rp[n]=nE.
__global__ __launch_bounds__(128) void k_bscan(const int* __restrict__ bcnt, int* __restrict__ bbase,
                                               int* __restrict__ gcur, int* __restrict__ rp, int n, int nE) {
  int t = threadIdx.x;
  int v = (t < NB) ? bcnt[t] : 0;
  __shared__ int sh[128];
  sh[t] = v; __syncthreads();
  for (int off = 1; off < 128; off <<= 1) {
    int u = (t >= off) ? sh[t - off] : 0; __syncthreads();
    sh[t] += u; __syncthreads();
  }
  int excl = sh[t] - v;
  if (t < NB) { bbase[t] = excl; gcur[t] = excl; }
  if (t == 0) { bbase[NB] = nE; rp[n] = nE; }
}

// Bin edges into bucket-ordered (src,dst) array. Per-block: local hist -> one
// cursor grab per bucket -> scatter into contiguous per-(bucket,block) regions.
__global__ __launch_bounds__(256) void k_bin(const int* __restrict__ src, const int* __restrict__ dst,
                                             int* __restrict__ gcur, int2* __restrict__ binned, int nE) {
  __shared__ int h[NB];
  __shared__ int off[NB];
  int t = threadIdx.x;
  int b0 = blockIdx.x * BIN_T;
  int b1 = b0 + BIN_T; if (b1 > nE) b1 = nE;
  if (t < NB) h[t] = 0;
  __syncthreads();
  for (int e = b0 + t; e < b1; e += 256)
    atomicAdd(&h[dst[e] >> BSHIFT], 1);
  __syncthreads();
  if (t < NB && h[t] > 0) off[t] = atomicAdd(&gcur[t], h[t]);
  __syncthreads();
  for (int e = b0 + t; e < b1; e += 256) {
    int s = src[e], d = dst[e];
    int p = atomicAdd(&off[d >> BSHIFT], 1);
    binned[p] = make_int2(s, d);
  }
}

// Block-per-bucket: local degree hist -> LDS scan -> rp + dis (fused) -> fill csrc.
__global__ __launch_bounds__(1024) void k_fillb(const int2* __restrict__ binned, const int* __restrict__ bbase,
                                                int* __restrict__ rp, float* __restrict__ dis,
                                                int* __restrict__ csrc, int n) {
  __shared__ int hist[1024];
  __shared__ int sbuf[1024];
  int b = blockIdx.x;
  int base = b << BSHIFT;
  int t = threadIdx.x;
  int lo = bbase[b], hi = bbase[b + 1];
  hist[t] = 0;
  __syncthreads();
  for (int e = lo + t; e < hi; e += 1024) {
    int2 p = binned[e];
    atomicAdd(&hist[p.y - base], 1);
  }
  __syncthreads();
  int v = hist[t];
  sbuf[t] = v; __syncthreads();
  for (int off = 1; off < 1024; off <<= 1) {
    int u = (t >= off) ? sbuf[t - off] : 0; __syncthreads();
    sbuf[t] += u; __syncthreads();
  }
  int excl = sbuf[t] - v;
  if (base + t < n) {
    rp[base + t] = lo + excl;
    dis[base + t] = rsqrtf((float)(v + 1));
  }
  __syncthreads();
  hist[t] = lo + excl;   // absolute write cursor per node
  __syncthreads();
  for (int e = lo + t; e < hi; e += 1024) {
    int2 p = binned[e];
    int pos = atomicAdd(&hist[p.y - base], 1);
    csrc[pos] = p.x;
  }
}

// y1 = dis[i] * (dropout(x) @ W1).  16 nodes/block.
__global__ __launch_bounds__(256) void k_xw(const float* __restrict__ x, const float* __restrict__ W1,
                                            const float* __restrict__ dis, float* __restrict__ y1, int n) {
  __shared__ float W1s[NF * NH];
  __shared__ float xs[16][132];
  int t = threadIdx.x;
  for (int i = t; i < NF * NH / 4; i += 256) ((float4*)W1s)[i] = ((const float4*)W1)[i];
  int nodeBase = blockIdx.x * 16;
  {
    int ebase = nodeBase * NF + t * 8;
    const float4* xp = (const float4*)x;
    float4 a = xp[(ebase >> 2)];
    float4 b = xp[(ebase >> 2) + 1];
    float v[8] = {a.x, a.y, a.z, a.w, b.x, b.y, b.z, b.w};
    int nloc = t >> 4, kbase = (t & 15) * 8;
#pragma unroll
    for (int q = 0; q < 8; ++q) {
      unsigned idx = (unsigned)(ebase + q);
      bool keep = (threefry_bits(idx) & 0x80000000u) == 0u;
      xs[nloc][kbase + q] = keep ? v[q] * 2.0f : 0.0f;
    }
  }
  __syncthreads();
  int wv = t >> 6, lane = t & 63;
  int nsub = lane >> 4, jg = lane & 15;
  int nloc = wv * 4 + nsub;
  int i = nodeBase + nloc;
  float4 acc = {0.f, 0.f, 0.f, 0.f};
  const float4* W4 = (const float4*)W1s;
  const float4* xr = (const float4*)&xs[nloc][0];
#pragma unroll 4
  for (int k4 = 0; k4 < NF / 4; ++k4) {
    float4 xv = xr[k4];
#pragma unroll
    for (int kk = 0; kk < 4; ++kk) {
      float4 w = W4[(k4 * 4 + kk) * 16 + jg];
      float xk = (&xv.x)[kk];
      acc.x += xk * w.x; acc.y += xk * w.y; acc.z += xk * w.z; acc.w += xk * w.w;
    }
  }
  float di = dis[i];
  acc.x *= di; acc.y *= di; acc.z *= di; acc.w *= di;
  ((float4*)y1)[i * 16 + jg] = acc;
}

// h = relu( dis[i] * (sum_{in} y1[src] + y1[i]) + b1 ).  Wave/node, lane=feature.
__global__ __launch_bounds__(256) void k_agg1(const float* __restrict__ y1, const int* __restrict__ rp,
                                              const int* __restrict__ csrc, const float* __restrict__ dis,
                                              const float* __restrict__ b1, float* __restrict__ h, int n) {
  int i = blockIdx.x * 4 + (threadIdx.x >> 6);
  if (i >= n) return;
  int lane = threadIdx.x & 63;
  float acc = y1[i * NH + lane];
  float a0 = 0.f, a1 = 0.f, a2 = 0.f, a3 = 0.f, a4 = 0.f, a5 = 0.f, a6 = 0.f, a7 = 0.f;
  int lo = rp[i], hi = rp[i + 1];
  for (int e0 = lo; e0 < hi; e0 += 64) {
    int e = e0 + lane;
    int sv = (e < hi) ? csrc[e] : 0;
    int cnt = hi - e0; if (cnt > 64) cnt = 64;
    int tt = 0;
    for (; tt + 8 <= cnt; tt += 8) {
      int s0 = __shfl(sv, tt + 0), s1 = __shfl(sv, tt + 1), s2 = __shfl(sv, tt + 2), s3 = __shfl(sv, tt + 3);
      int s4 = __shfl(sv, tt + 4), s5 = __shfl(sv, tt + 5), s6 = __shfl(sv, tt + 6), s7 = __shfl(sv, tt + 7);
      float v0 = y1[s0 * NH + lane], v1 = y1[s1 * NH + lane], v2 = y1[s2 * NH + lane], v3 = y1[s3 * NH + lane];
      float v4 = y1[s4 * NH + lane], v5 = y1[s5 * NH + lane], v6 = y1[s6 * NH + lane], v7 = y1[s7 * NH + lane];
      a0 += v0; a1 += v1; a2 += v2; a3 += v3; a4 += v4; a5 += v5; a6 += v6; a7 += v7;
    }
    for (; tt + 4 <= cnt; tt += 4) {
      int s0 = __shfl(sv, tt + 0), s1 = __shfl(sv, tt + 1), s2 = __shfl(sv, tt + 2), s3 = __shfl(sv, tt + 3);
      float v0 = y1[s0 * NH + lane], v1 = y1[s1 * NH + lane], v2 = y1[s2 * NH + lane], v3 = y1[s3 * NH + lane];
      a0 += v0; a1 += v1; a2 += v2; a3 += v3;
    }
    for (; tt < cnt; ++tt) {
      int s = __shfl(sv, tt);
      acc += y1[s * NH + lane];
    }
  }
  acc += ((a0 + a1) + (a2 + a3)) + ((a4 + a5) + (a6 + a7));
  h[i * NH + lane] = fmaxf(fmaf(dis[i], acc, b1[lane]), 0.f);
}

// y2 = dis[i] * (h @ W2)
__global__ __launch_bounds__(256) void k_hw(const float* __restrict__ h, const float* __restrict__ W2,
                                            const float* __restrict__ dis, float* __restrict__ y2, int n) {
  __shared__ float W2s[NH * NC];
  __shared__ float hs[16][68];
  int t = threadIdx.x;
  for (int i = t; i < NH * NC / 4; i += 256) ((float4*)W2s)[i] = ((const float4*)W2)[i];
  int nodeBase = blockIdx.x * 16;
  {
    const float4* hp = (const float4*)(h + nodeBase * NH);
    float4 v = hp[t];
    *(float4*)&hs[t >> 4][(t & 15) * 4] = v;
  }
  __syncthreads();
  int wv = t >> 6, lane = t & 63;
  int nsub = lane >> 4, jg = lane & 15;
  int nloc = wv * 4 + nsub;
  int i = nodeBase + nloc;
  if (jg < 10) {
    float4 acc = {0.f, 0.f, 0.f, 0.f};
    const float4* xr = (const float4*)&hs[nloc][0];
#pragma unroll 4
    for (int k4 = 0; k4 < NH / 4; ++k4) {
      float4 xv = xr[k4];
#pragma unroll
      for (int kk = 0; kk < 4; ++kk) {
        float4 w = *(const float4*)&W2s[(k4 * 4 + kk) * NC + jg * 4];
        float xk = (&xv.x)[kk];
        acc.x += xk * w.x; acc.y += xk * w.y; acc.z += xk * w.z; acc.w += xk * w.w;
      }
    }
    float di = dis[i];
    acc.x *= di; acc.y *= di; acc.z *= di; acc.w *= di;
    *(float4*)(y2 + i * NC + jg * 4) = acc;
  }
}

// out = dis[i] * (sum_{in} y2[src] + y2[i]) + b2.  Lanes 0..39 = features.
__global__ __launch_bounds__(256) void k_agg2(const float* __restrict__ y2, const int* __restrict__ rp,
                                              const int* __restrict__ csrc, const float* __restrict__ dis,
                                              const float* __restrict__ b2, float* __restrict__ out, int n) {
  int i = blockIdx.x * 4 + (threadIdx.x >> 6);
  if (i >= n) return;
  int lane = threadIdx.x & 63;
  bool act = lane < NC;
  float acc = act ? y2[i * NC + lane] : 0.f;
  float a0 = 0.f, a1 = 0.f, a2 = 0.f, a3 = 0.f, a4 = 0.f, a5 = 0.f, a6 = 0.f, a7 = 0.f;
  int lo = rp[i], hi = rp[i + 1];
  for (int e0 = lo; e0 < hi; e0 += 64) {
    int e = e0 + lane;
    int sv = (e < hi) ? csrc[e] : 0;
    int cnt = hi - e0; if (cnt > 64) cnt = 64;
    int tt = 0;
    for (; tt + 8 <= cnt; tt += 8) {
      int s0 = __shfl(sv, tt + 0), s1 = __shfl(sv, tt + 1), s2 = __shfl(sv, tt + 2), s3 = __shfl(sv, tt + 3);
      int s4 = __shfl(sv, tt + 4), s5 = __shfl(sv, tt + 5), s6 = __shfl(sv, tt + 6), s7 = __shfl(sv, tt + 7);
      if (act) {
        float v0 = y2[s0 * NC + lane], v1 = y2[s1 * NC + lane], v2 = y2[s2 * NC + lane], v3 = y2[s3 * NC + lane];
        float v4 = y2[s4 * NC + lane], v5 = y2[s5 * NC + lane], v6 = y2[s6 * NC + lane], v7 = y2[s7 * NC + lane];
        a0 += v0; a1 += v1; a2 += v2; a3 += v3; a4 += v4; a5 += v5; a6 += v6; a7 += v7;
      }
    }
    for (; tt + 4 <= cnt; tt += 4) {
      int s0 = __shfl(sv, tt + 0), s1 = __shfl(sv, tt + 1), s2 = __shfl(sv, tt + 2), s3 = __shfl(sv, tt + 3);
      if (act) {
        float v0 = y2[s0 * NC + lane], v1 = y2[s1 * NC + lane], v2 = y2[s2 * NC + lane], v3 = y2[s3 * NC + lane];
        a0 += v0; a1 += v1; a2 += v2; a3 += v3;
      }
    }
    for (; tt < cnt; ++tt) {
      int s = __shfl(sv, tt);
      if (act) acc += y2[s * NC + lane];
    }
  }
  if (act) {
    acc += ((a0 + a1) + (a2 + a3)) + ((a4 + a5) + (a6 + a7));
    out[i * NC + lane] = fmaf(dis[i], acc, b2[lane]);
  }
}

extern "C" void kernel_launch(void* const* d_in, const int* in_sizes, int n_in,
                              void* d_out, int out_size, void* d_ws, size_t ws_size,
                              hipStream_t stream) {
  const float* x  = (const float*)d_in[0];
  const int*   ei = (const int*)d_in[1];
  const float* W1 = (const float*)d_in[2];
  const float* b1 = (const float*)d_in[3];
  const float* W2 = (const float*)d_in[4];
  const float* b2 = (const float*)d_in[5];
  float* out = (float*)d_out;
  int n  = in_sizes[0] / NF;    // 100000
  int nE = in_sizes[1] / 2;     // 1600000
  const int* src = ei;
  const int* dst = ei + nE;

  char* ws = (char*)d_ws;
  float* dis   = (float*)(ws + 0);          // 400 KB
  int*   rp    = (int*)(ws + 400000);       // n+1 ints
  int*   bcnt  = (int*)(ws + 800128);       // NB ints
  int*   bbase = (int*)(ws + 800640);       // NB+1 ints
  int*   gcur  = (int*)(ws + 801152);       // NB ints
  int*   csrc  = (int*)(ws + 801664);       // 6.4 MB
  float* y1    = (float*)(ws + 7201664);    // 25.6 MB
  float* h     = (float*)(ws + 32801664);   // 25.6 MB
  int2*  binned = (int2*)(ws + 32801664);   // 12.8 MB, overlays h (dead before agg1)
  float* y2    = y1;                        // y1 dead after agg1

  hipMemsetAsync(bcnt, 0, NB * 4, stream);

  k_bhist<<<512, 256, 0, stream>>>(dst, bcnt, nE);
  k_bscan<<<1, 128, 0, stream>>>(bcnt, bbase, gcur, rp, n, nE);
  k_bin  <<<(nE + BIN_T - 1) / BIN_T, 256, 0, stream>>>(src, dst, gcur, binned, nE);
  k_fillb<<<NB, 1024, 0, stream>>>(binned, bbase, rp, dis, csrc, n);
  k_xw   <<<n / 16, 256, 0, stream>>>(x, W1, dis, y1, n);
  k_agg1 <<<(n + 3) / 4, 256, 0, stream>>>(y1, rp, csrc, dis, b1, h, n);
  k_hw   <<<n / 16, 256, 0, stream>>>(h, W2, dis, y2, n);
  k_agg2 <<<(n + 3) / 4, 256, 0, stream>>>(y2, rp, csrc, dis, b2, out, n);
}

// Round 5
// 293.210 us; speedup vs baseline: 2.2234x; 1.1545x over previous
//
#include <hip/hip_runtime.h>

#define NF 128
#define NH 64
#define NC 40
#define BSHIFT 10                 // bucket = dst >> 10  (1024 nodes/bucket)
#define NB 98                     // ceil(100000 / 1024)
#define BIN_T 8192                // edges per k_bin block

typedef __attribute__((ext_vector_type(8))) short short8;
typedef __attribute__((ext_vector_type(4))) float float4v;

__device__ __forceinline__ unsigned rotl32(unsigned v, int s) { return (v << s) | (v >> (32 - s)); }

__device__ __forceinline__ unsigned short f2bf(float f) {   // fp32 -> bf16 RNE
  unsigned u = __float_as_uint(f);
  return (unsigned short)((u + 0x7FFFu + ((u >> 16) & 1u)) >> 16);
}
__device__ __forceinline__ float bf2f(unsigned short b) {
  return __uint_as_float(((unsigned)b) << 16);
}

// threefry2x32, key(0,42), partitionable path: bits = x0^x1 of counter (0, idx).
__device__ __forceinline__ unsigned threefry_bits(unsigned idx) {
  const unsigned k0 = 0u, k1 = 42u;
  const unsigned k2x = 0u ^ 42u ^ 0x1BD11BDAu;
  unsigned x0 = 0u, x1 = idx;
  x0 += k0; x1 += k1;
  x0 += x1; x1 = rotl32(x1, 13); x1 ^= x0;
  x0 += x1; x1 = rotl32(x1, 15); x1 ^= x0;
  x0 += x1; x1 = rotl32(x1, 26); x1 ^= x0;
  x0 += x1; x1 = rotl32(x1, 6);  x1 ^= x0;
  x0 += k1; x1 += k2x + 1u;
  x0 += x1; x1 = rotl32(x1, 17); x1 ^= x0;
  x0 += x1; x1 = rotl32(x1, 29); x1 ^= x0;
  x0 += x1; x1 = rotl32(x1, 16); x1 ^= x0;
  x0 += x1; x1 = rotl32(x1, 24); x1 ^= x0;
  x0 += k2x; x1 += k0 + 2u;
  x0 += x1; x1 = rotl32(x1, 13); x1 ^= x0;
  x0 += x1; x1 = rotl32(x1, 15); x1 ^= x0;
  x0 += x1; x1 = rotl32(x1, 26); x1 ^= x0;
  x0 += x1; x1 = rotl32(x1, 6);  x1 ^= x0;
  x0 += k0; x1 += k1 + 3u;
  x0 += x1; x1 = rotl32(x1, 17); x1 ^= x0;
  x0 += x1; x1 = rotl32(x1, 29); x1 ^= x0;
  x0 += x1; x1 = rotl32(x1, 16); x1 ^= x0;
  x0 += x1; x1 = rotl32(x1, 24); x1 ^= x0;
  x0 += k1; x1 += k2x + 4u;
  x0 += x1; x1 = rotl32(x1, 13); x1 ^= x0;
  x0 += x1; x1 = rotl32(x1, 15); x1 ^= x0;
  x0 += x1; x1 = rotl32(x1, 26); x1 ^= x0;
  x0 += x1; x1 = rotl32(x1, 6);  x1 ^= x0;
  x0 += k2x; x1 += k0 + 5u;
  return x0 ^ x1;
}

// One-shot: W1 -> bf16 transposed [c][k] (128k x 64c); W2 -> bf16 transposed padded [c<48][k<64].
__global__ __launch_bounds__(256) void k_prep(const float* __restrict__ W1, const float* __restrict__ W2,
                                              unsigned short* __restrict__ Wt1b, unsigned short* __restrict__ Wt2b) {
  int id = blockIdx.x * 256 + threadIdx.x;
  if (id < NF * NH) {                      // 8192
    int k = id >> 6, c = id & 63;
    Wt1b[c * NF + k] = f2bf(W1[id]);
  } else if (id < NF * NH + 48 * NH) {     // 3072
    int id2 = id - NF * NH;
    int c = id2 >> 6, k = id2 & 63;
    Wt2b[c * NH + k] = (c < NC) ? f2bf(W2[k * NC + c]) : 0;
  }
}

// Global bucket histogram (LDS-staged).
__global__ __launch_bounds__(256) void k_bhist(const int* __restrict__ dst, int* __restrict__ bcnt, int nE) {
  __shared__ int h[NB];
  int t = threadIdx.x;
  if (t < NB) h[t] = 0;
  __syncthreads();
  int stride = gridDim.x * 256;
  for (int e = blockIdx.x * 256 + t; e < nE; e += stride)
    atomicAdd(&h[dst[e] >> BSHIFT], 1);
  __syncthreads();
  if (t < NB && h[t]) atomicAdd(&bcnt[t], h[t]);
}

__global__ __launch_bounds__(128) void k_bscan(const int* __restrict__ bcnt, int* __restrict__ bbase,
                                               int* __restrict__ gcur, int* __restrict__ rp, int n, int nE) {
  int t = threadIdx.x;
  int v = (t < NB) ? bcnt[t] : 0;
  __shared__ int sh[128];
  sh[t] = v; __syncthreads();
  for (int off = 1; off < 128; off <<= 1) {
    int u = (t >= off) ? sh[t - off] : 0; __syncthreads();
    sh[t] += u; __syncthreads();
  }
  int excl = sh[t] - v;
  if (t < NB) { bbase[t] = excl; gcur[t] = excl; }
  if (t == 0) { bbase[NB] = nE; rp[n] = nE; }
}

__global__ __launch_bounds__(256) void k_bin(const int* __restrict__ src, const int* __restrict__ dst,
                                             int* __restrict__ gcur, int2* __restrict__ binned, int nE) {
  __shared__ int h[NB];
  __shared__ int off[NB];
  int t = threadIdx.x;
  int b0 = blockIdx.x * BIN_T;
  int b1 = b0 + BIN_T; if (b1 > nE) b1 = nE;
  if (t < NB) h[t] = 0;
  __syncthreads();
  for (int e = b0 + t; e < b1; e += 256)
    atomicAdd(&h[dst[e] >> BSHIFT], 1);
  __syncthreads();
  if (t < NB && h[t] > 0) off[t] = atomicAdd(&gcur[t], h[t]);
  __syncthreads();
  for (int e = b0 + t; e < b1; e += 256) {
    int s = src[e], d = dst[e];
    int p = atomicAdd(&off[d >> BSHIFT], 1);
    binned[p] = make_int2(s, d);
  }
}

__global__ __launch_bounds__(1024) void k_fillb(const int2* __restrict__ binned, const int* __restrict__ bbase,
                                                int* __restrict__ rp, float* __restrict__ dis,
                                                int* __restrict__ csrc, int n) {
  __shared__ int hist[1024];
  __shared__ int sbuf[1024];
  int b = blockIdx.x;
  int base = b << BSHIFT;
  int t = threadIdx.x;
  int lo = bbase[b], hi = bbase[b + 1];
  hist[t] = 0;
  __syncthreads();
  for (int e = lo + t; e < hi; e += 1024) {
    int2 p = binned[e];
    atomicAdd(&hist[p.y - base], 1);
  }
  __syncthreads();
  int v = hist[t];
  sbuf[t] = v; __syncthreads();
  for (int off = 1; off < 1024; off <<= 1) {
    int u = (t >= off) ? sbuf[t - off] : 0; __syncthreads();
    sbuf[t] += u; __syncthreads();
  }
  int excl = sbuf[t] - v;
  if (base + t < n) {
    rp[base + t] = lo + excl;
    dis[base + t] = rsqrtf((float)(v + 1));
  }
  __syncthreads();
  hist[t] = lo + excl;
  __syncthreads();
  for (int e = lo + t; e < hi; e += 1024) {
    int2 p = binned[e];
    int pos = atomicAdd(&hist[p.y - base], 1);
    csrc[pos] = p.x;
  }
}

// y1 = bf16( dis[i] * (dropout(x) @ W1) ) via MFMA bf16.
// 16 nodes/block, 4 waves; wave w computes 16-col tile w.
__global__ __launch_bounds__(256) void k_xw(const float* __restrict__ x, const unsigned short* __restrict__ Wt1b,
                                            const float* __restrict__ dis, unsigned short* __restrict__ y1b, int n) {
  __shared__ unsigned short Ws[NH * 136];   // Wt1 [c][k], padded k-stride 136
  __shared__ unsigned short xs[16 * 136];   // x tile [node][k] bf16, padded
  int t = threadIdx.x;
  int nodeBase = blockIdx.x * 16;
  // stage Wt1 (16 KB) into LDS with stride 136
  for (int id = t; id < NH * 16; id += 256) {      // 1024 chunks of 8 bf16
    int c = id >> 4, kc = id & 15;
    *(short8*)&Ws[c * 136 + kc * 8] = *(const short8*)&Wt1b[c * NF + kc * 8];
  }
  // stage dropout(x) tile as bf16
  {
    int nloc = t >> 4, kbase = (t & 15) * 8;
    int ebase = (nodeBase + nloc) * NF + kbase;
    const float4* xp = (const float4*)x;
    float4 a = xp[(ebase >> 2)];
    float4 b = xp[(ebase >> 2) + 1];
    float v[8] = {a.x, a.y, a.z, a.w, b.x, b.y, b.z, b.w};
#pragma unroll
    for (int q = 0; q < 8; ++q) {
      unsigned idx = (unsigned)(ebase + q);
      bool keep = (threefry_bits(idx) & 0x80000000u) == 0u;
      xs[nloc * 136 + kbase + q] = keep ? f2bf(v[q] * 2.0f) : 0;
    }
  }
  __syncthreads();
  int w = t >> 6, lane = t & 63;
  int m = lane & 15, quad = lane >> 4;
  float4v acc = {0.f, 0.f, 0.f, 0.f};
#pragma unroll
  for (int ks = 0; ks < 4; ++ks) {
    short8 a = *(const short8*)&xs[m * 136 + ks * 32 + quad * 8];
    short8 b = *(const short8*)&Ws[(w * 16 + m) * 136 + ks * 32 + quad * 8];
    acc = __builtin_amdgcn_mfma_f32_16x16x32_bf16(a, b, acc, 0, 0, 0);
  }
#pragma unroll
  for (int r = 0; r < 4; ++r) {
    int node = nodeBase + quad * 4 + r;
    y1b[node * NH + w * 16 + m] = f2bf(acc[r] * dis[node]);
  }
}

// h = bf16(relu( dis[i]*(sum y1[src] + y1[i]) + b1 )).  Wave/node, lane=feature. bf16 gathers.
__global__ __launch_bounds__(256) void k_agg1(const unsigned short* __restrict__ y1b, const int* __restrict__ rp,
                                              const int* __restrict__ csrc, const float* __restrict__ dis,
                                              const float* __restrict__ b1, unsigned short* __restrict__ hb, int n) {
  int i = blockIdx.x * 4 + (threadIdx.x >> 6);
  if (i >= n) return;
  int lane = threadIdx.x & 63;
  float acc = bf2f(y1b[i * NH + lane]);
  float a0 = 0.f, a1 = 0.f, a2 = 0.f, a3 = 0.f, a4 = 0.f, a5 = 0.f, a6 = 0.f, a7 = 0.f;
  int lo = rp[i], hi = rp[i + 1];
  for (int e0 = lo; e0 < hi; e0 += 64) {
    int e = e0 + lane;
    int sv = (e < hi) ? csrc[e] : 0;
    int cnt = hi - e0; if (cnt > 64) cnt = 64;
    int tt = 0;
    for (; tt + 8 <= cnt; tt += 8) {
      int s0 = __shfl(sv, tt + 0), s1 = __shfl(sv, tt + 1), s2 = __shfl(sv, tt + 2), s3 = __shfl(sv, tt + 3);
      int s4 = __shfl(sv, tt + 4), s5 = __shfl(sv, tt + 5), s6 = __shfl(sv, tt + 6), s7 = __shfl(sv, tt + 7);
      float v0 = bf2f(y1b[s0 * NH + lane]), v1 = bf2f(y1b[s1 * NH + lane]);
      float v2 = bf2f(y1b[s2 * NH + lane]), v3 = bf2f(y1b[s3 * NH + lane]);
      float v4 = bf2f(y1b[s4 * NH + lane]), v5 = bf2f(y1b[s5 * NH + lane]);
      float v6 = bf2f(y1b[s6 * NH + lane]), v7 = bf2f(y1b[s7 * NH + lane]);
      a0 += v0; a1 += v1; a2 += v2; a3 += v3; a4 += v4; a5 += v5; a6 += v6; a7 += v7;
    }
    for (; tt + 4 <= cnt; tt += 4) {
      int s0 = __shfl(sv, tt + 0), s1 = __shfl(sv, tt + 1), s2 = __shfl(sv, tt + 2), s3 = __shfl(sv, tt + 3);
      float v0 = bf2f(y1b[s0 * NH + lane]), v1 = bf2f(y1b[s1 * NH + lane]);
      float v2 = bf2f(y1b[s2 * NH + lane]), v3 = bf2f(y1b[s3 * NH + lane]);
      a0 += v0; a1 += v1; a2 += v2; a3 += v3;
    }
    for (; tt < cnt; ++tt) {
      int s = __shfl(sv, tt);
      acc += bf2f(y1b[s * NH + lane]);
    }
  }
  acc += ((a0 + a1) + (a2 + a3)) + ((a4 + a5) + (a6 + a7));
  hb[i * NH + lane] = f2bf(fmaxf(fmaf(dis[i], acc, b1[lane]), 0.f));
}

// y2 = bf16( dis[i] * (h @ W2) ) via MFMA bf16.  16 nodes/block, 3 waves (48 padded cols).
__global__ __launch_bounds__(192) void k_hw(const unsigned short* __restrict__ hb, const unsigned short* __restrict__ Wt2b,
                                            const float* __restrict__ dis, unsigned short* __restrict__ y2b, int n) {
  __shared__ unsigned short Ws[48 * 72];    // Wt2 [c][k] padded k-stride 72
  __shared__ unsigned short xs[16 * 72];    // h tile
  int t = threadIdx.x;
  int nodeBase = blockIdx.x * 16;
  for (int id = t; id < 48 * 8; id += 192) {       // 384 chunks
    int c = id >> 3, kc = id & 7;
    *(short8*)&Ws[c * 72 + kc * 8] = *(const short8*)&Wt2b[c * NH + kc * 8];
  }
  if (t < 128) {                                   // 128 chunks for 16x64 tile
    int c = t >> 3, kc = t & 7;
    *(short8*)&xs[c * 72 + kc * 8] = *(const short8*)&hb[(nodeBase + c) * NH + kc * 8];
  }
  __syncthreads();
  int w = t >> 6, lane = t & 63;
  int m = lane & 15, quad = lane >> 4;
  float4v acc = {0.f, 0.f, 0.f, 0.f};
#pragma unroll
  for (int ks = 0; ks < 2; ++ks) {
    short8 a = *(const short8*)&xs[m * 72 + ks * 32 + quad * 8];
    short8 b = *(const short8*)&Ws[(w * 16 + m) * 72 + ks * 32 + quad * 8];
    acc = __builtin_amdgcn_mfma_f32_16x16x32_bf16(a, b, acc, 0, 0, 0);
  }
  int col = w * 16 + m;
  if (col < NC) {
#pragma unroll
    for (int r = 0; r < 4; ++r) {
      int node = nodeBase + quad * 4 + r;
      y2b[node * NC + col] = f2bf(acc[r] * dis[node]);
    }
  }
}

// out = dis[i]*(sum y2[src] + y2[i]) + b2  (fp32 out).  Lanes 0..39 = features.
__global__ __launch_bounds__(256) void k_agg2(const unsigned short* __restrict__ y2b, const int* __restrict__ rp,
                                              const int* __restrict__ csrc, const float* __restrict__ dis,
                                              const float* __restrict__ b2, float* __restrict__ out, int n) {
  int i = blockIdx.x * 4 + (threadIdx.x >> 6);
  if (i >= n) return;
  int lane = threadIdx.x & 63;
  bool act = lane < NC;
  float acc = act ? bf2f(y2b[i * NC + lane]) : 0.f;
  float a0 = 0.f, a1 = 0.f, a2 = 0.f, a3 = 0.f, a4 = 0.f, a5 = 0.f, a6 = 0.f, a7 = 0.f;
  int lo = rp[i], hi = rp[i + 1];
  for (int e0 = lo; e0 < hi; e0 += 64) {
    int e = e0 + lane;
    int sv = (e < hi) ? csrc[e] : 0;
    int cnt = hi - e0; if (cnt > 64) cnt = 64;
    int tt = 0;
    for (; tt + 8 <= cnt; tt += 8) {
      int s0 = __shfl(sv, tt + 0), s1 = __shfl(sv, tt + 1), s2 = __shfl(sv, tt + 2), s3 = __shfl(sv, tt + 3);
      int s4 = __shfl(sv, tt + 4), s5 = __shfl(sv, tt + 5), s6 = __shfl(sv, tt + 6), s7 = __shfl(sv, tt + 7);
      if (act) {
        float v0 = bf2f(y2b[s0 * NC + lane]), v1 = bf2f(y2b[s1 * NC + lane]);
        float v2 = bf2f(y2b[s2 * NC + lane]), v3 = bf2f(y2b[s3 * NC + lane]);
        float v4 = bf2f(y2b[s4 * NC + lane]), v5 = bf2f(y2b[s5 * NC + lane]);
        float v6 = bf2f(y2b[s6 * NC + lane]), v7 = bf2f(y2b[s7 * NC + lane]);
        a0 += v0; a1 += v1; a2 += v2; a3 += v3; a4 += v4; a5 += v5; a6 += v6; a7 += v7;
      }
    }
    for (; tt + 4 <= cnt; tt += 4) {
      int s0 = __shfl(sv, tt + 0), s1 = __shfl(sv, tt + 1), s2 = __shfl(sv, tt + 2), s3 = __shfl(sv, tt + 3);
      if (act) {
        float v0 = bf2f(y2b[s0 * NC + lane]), v1 = bf2f(y2b[s1 * NC + lane]);
        float v2 = bf2f(y2b[s2 * NC + lane]), v3 = bf2f(y2b[s3 * NC + lane]);
        a0 += v0; a1 += v1; a2 += v2; a3 += v3;
      }
    }
    for (; tt < cnt; ++tt) {
      int s = __shfl(sv, tt);
      if (act) acc += bf2f(y2b[s * NC + lane]);
    }
  }
  if (act) {
    acc += ((a0 + a1) + (a2 + a3)) + ((a4 + a5) + (a6 + a7));
    out[i * NC + lane] = fmaf(dis[i], acc, b2[lane]);
  }
}

extern "C" void kernel_launch(void* const* d_in, const int* in_sizes, int n_in,
                              void* d_out, int out_size, void* d_ws, size_t ws_size,
                              hipStream_t stream) {
  const float* x  = (const float*)d_in[0];
  const int*   ei = (const int*)d_in[1];
  const float* W1 = (const float*)d_in[2];
  const float* b1 = (const float*)d_in[3];
  const float* W2 = (const float*)d_in[4];
  const float* b2 = (const float*)d_in[5];
  float* out = (float*)d_out;
  int n  = in_sizes[0] / NF;    // 100000
  int nE = in_sizes[1] / 2;     // 1600000
  const int* src = ei;
  const int* dst = ei + nE;

  char* ws = (char*)d_ws;
  float* dis   = (float*)(ws + 0);                    // 400 KB
  int*   rp    = (int*)(ws + 400000);                 // n+1 ints
  int*   bcnt  = (int*)(ws + 800128);
  int*   bbase = (int*)(ws + 800640);
  int*   gcur  = (int*)(ws + 801152);
  unsigned short* Wt1b = (unsigned short*)(ws + 801664);   // 16384 B
  unsigned short* Wt2b = (unsigned short*)(ws + 818048);   // 6144 B
  int*   csrc  = (int*)(ws + 824192);                 // 6.4 MB
  unsigned short* y1b = (unsigned short*)(ws + 7224192);   // 12.8 MB
  unsigned short* hb  = (unsigned short*)(ws + 20024192);  // 12.8 MB
  int2*  binned = (int2*)(ws + 20024192);             // 12.8 MB, overlays hb (dead before agg1)
  unsigned short* y2b = y1b;                          // y1 dead after agg1 (8 MB needed)

  hipMemsetAsync(bcnt, 0, NB * 4, stream);

  k_prep <<<(NF * NH + 48 * NH + 255) / 256, 256, 0, stream>>>(W1, W2, Wt1b, Wt2b);
  k_bhist<<<512, 256, 0, stream>>>(dst, bcnt, nE);
  k_bscan<<<1, 128, 0, stream>>>(bcnt, bbase, gcur, rp, n, nE);
  k_bin  <<<(nE + BIN_T - 1) / BIN_T, 256, 0, stream>>>(src, dst, gcur, binned, nE);
  k_fillb<<<NB, 1024, 0, stream>>>(binned, bbase, rp, dis, csrc, n);
  k_xw   <<<n / 16, 256, 0, stream>>>(x, Wt1b, dis, y1b, n);
  k_agg1 <<<(n + 3) / 4, 256, 0, stream>>>(y1b, rp, csrc, dis, b1, hb, n);
  k_hw   <<<n / 16, 192, 0, stream>>>(hb, Wt2b, dis, y2b, n);
  k_agg2 <<<(n + 3) / 4, 256, 0, stream>>>(y2b, rp, csrc, dis, b2, out, n);
}

// Round 6
// 278.418 us; speedup vs baseline: 2.3415x; 1.0531x over previous
//
#include <hip/hip_runtime.h>

#define NF 128
#define NH 64
#define NC 40
#define BSHIFT 10                 // bucket = dst >> 10  (1024 nodes/bucket)
#define NB 98                     // ceil(100000 / 1024)
#define BIN_T 8192                // edges per k_bin block

typedef __attribute__((ext_vector_type(8))) short short8;
typedef __attribute__((ext_vector_type(4))) float float4v;

__device__ __forceinline__ unsigned rotl32(unsigned v, int s) { return (v << s) | (v >> (32 - s)); }

__device__ __forceinline__ unsigned short f2bf(float f) {   // fp32 -> bf16 RNE
  unsigned u = __float_as_uint(f);
  return (unsigned short)((u + 0x7FFFu + ((u >> 16) & 1u)) >> 16);
}
__device__ __forceinline__ float bf2f(unsigned short b) {
  return __uint_as_float(((unsigned)b) << 16);
}

// threefry2x32, key(0,42), partitionable path: bits = x0^x1 of counter (0, idx).
__device__ __forceinline__ unsigned threefry_bits(unsigned idx) {
  const unsigned k0 = 0u, k1 = 42u;
  const unsigned k2x = 0u ^ 42u ^ 0x1BD11BDAu;
  unsigned x0 = 0u, x1 = idx;
  x0 += k0; x1 += k1;
  x0 += x1; x1 = rotl32(x1, 13); x1 ^= x0;
  x0 += x1; x1 = rotl32(x1, 15); x1 ^= x0;
  x0 += x1; x1 = rotl32(x1, 26); x1 ^= x0;
  x0 += x1; x1 = rotl32(x1, 6);  x1 ^= x0;
  x0 += k1; x1 += k2x + 1u;
  x0 += x1; x1 = rotl32(x1, 17); x1 ^= x0;
  x0 += x1; x1 = rotl32(x1, 29); x1 ^= x0;
  x0 += x1; x1 = rotl32(x1, 16); x1 ^= x0;
  x0 += x1; x1 = rotl32(x1, 24); x1 ^= x0;
  x0 += k2x; x1 += k0 + 2u;
  x0 += x1; x1 = rotl32(x1, 13); x1 ^= x0;
  x0 += x1; x1 = rotl32(x1, 15); x1 ^= x0;
  x0 += x1; x1 = rotl32(x1, 26); x1 ^= x0;
  x0 += x1; x1 = rotl32(x1, 6);  x1 ^= x0;
  x0 += k0; x1 += k1 + 3u;
  x0 += x1; x1 = rotl32(x1, 17); x1 ^= x0;
  x0 += x1; x1 = rotl32(x1, 29); x1 ^= x0;
  x0 += x1; x1 = rotl32(x1, 16); x1 ^= x0;
  x0 += x1; x1 = rotl32(x1, 24); x1 ^= x0;
  x0 += k1; x1 += k2x + 4u;
  x0 += x1; x1 = rotl32(x1, 13); x1 ^= x0;
  x0 += x1; x1 = rotl32(x1, 15); x1 ^= x0;
  x0 += x1; x1 = rotl32(x1, 26); x1 ^= x0;
  x0 += x1; x1 = rotl32(x1, 6);  x1 ^= x0;
  x0 += k2x; x1 += k0 + 5u;
  return x0 ^ x1;
}

// One-shot: W1 -> bf16 transposed [c][k]; W2 -> bf16 transposed padded [c<48][k<64].
__global__ __launch_bounds__(256) void k_prep(const float* __restrict__ W1, const float* __restrict__ W2,
                                              unsigned short* __restrict__ Wt1b, unsigned short* __restrict__ Wt2b) {
  int id = blockIdx.x * 256 + threadIdx.x;
  if (id < NF * NH) {
    int k = id >> 6, c = id & 63;
    Wt1b[c * NF + k] = f2bf(W1[id]);
  } else if (id < NF * NH + 48 * NH) {
    int id2 = id - NF * NH;
    int c = id2 >> 6, k = id2 & 63;
    Wt2b[c * NH + k] = (c < NC) ? f2bf(W2[k * NC + c]) : 0;
  }
}

__global__ __launch_bounds__(256) void k_bhist(const int* __restrict__ dst, int* __restrict__ bcnt, int nE) {
  __shared__ int h[NB];
  int t = threadIdx.x;
  if (t < NB) h[t] = 0;
  __syncthreads();
  int stride = gridDim.x * 256;
  for (int e = blockIdx.x * 256 + t; e < nE; e += stride)
    atomicAdd(&h[dst[e] >> BSHIFT], 1);
  __syncthreads();
  if (t < NB && h[t]) atomicAdd(&bcnt[t], h[t]);
}

__global__ __launch_bounds__(128) void k_bscan(const int* __restrict__ bcnt, int* __restrict__ bbase,
                                               int* __restrict__ gcur, int* __restrict__ rp, int n, int nE) {
  int t = threadIdx.x;
  int v = (t < NB) ? bcnt[t] : 0;
  __shared__ int sh[128];
  sh[t] = v; __syncthreads();
  for (int off = 1; off < 128; off <<= 1) {
    int u = (t >= off) ? sh[t - off] : 0; __syncthreads();
    sh[t] += u; __syncthreads();
  }
  int excl = sh[t] - v;
  if (t < NB) { bbase[t] = excl; gcur[t] = excl; }
  if (t == 0) { bbase[NB] = nE; rp[n] = nE; }
}

// Bin edges: packed word = (src<<10) | (dst & 1023).  src < 2^17, so fits 27 bits.
__global__ __launch_bounds__(256) void k_bin(const int* __restrict__ src, const int* __restrict__ dst,
                                             int* __restrict__ gcur, unsigned* __restrict__ binned, int nE) {
  __shared__ int h[NB];
  __shared__ int off[NB];
  int t = threadIdx.x;
  int b0 = blockIdx.x * BIN_T;
  int b1 = b0 + BIN_T; if (b1 > nE) b1 = nE;
  if (t < NB) h[t] = 0;
  __syncthreads();
  for (int e = b0 + t; e < b1; e += 256)
    atomicAdd(&h[dst[e] >> BSHIFT], 1);
  __syncthreads();
  if (t < NB && h[t] > 0) off[t] = atomicAdd(&gcur[t], h[t]);
  __syncthreads();
  for (int e = b0 + t; e < b1; e += 256) {
    int s = src[e], d = dst[e];
    int p = atomicAdd(&off[d >> BSHIFT], 1);
    binned[p] = ((unsigned)s << BSHIFT) | (unsigned)(d & ((1 << BSHIFT) - 1));
  }
}

__global__ __launch_bounds__(1024) void k_fillb(const unsigned* __restrict__ binned, const int* __restrict__ bbase,
                                                int* __restrict__ rp, float* __restrict__ dis,
                                                int* __restrict__ csrc, int n) {
  __shared__ int hist[1024];
  __shared__ int sbuf[1024];
  int b = blockIdx.x;
  int base = b << BSHIFT;
  int t = threadIdx.x;
  int lo = bbase[b], hi = bbase[b + 1];
  hist[t] = 0;
  __syncthreads();
  for (int e = lo + t; e < hi; e += 1024)
    atomicAdd(&hist[binned[e] & 1023u], 1);
  __syncthreads();
  int v = hist[t];
  sbuf[t] = v; __syncthreads();
  for (int off = 1; off < 1024; off <<= 1) {
    int u = (t >= off) ? sbuf[t - off] : 0; __syncthreads();
    sbuf[t] += u; __syncthreads();
  }
  int excl = sbuf[t] - v;
  if (base + t < n) {
    rp[base + t] = lo + excl;
    dis[base + t] = rsqrtf((float)(v + 1));
  }
  __syncthreads();
  hist[t] = lo + excl;
  __syncthreads();
  for (int e = lo + t; e < hi; e += 1024) {
    unsigned p = binned[e];
    int pos = atomicAdd(&hist[p & 1023u], 1);
    csrc[pos] = (int)(p >> BSHIFT);
  }
}

// y1 = bf16( dis[i] * (dropout(x) @ W1) ) via MFMA bf16.  16 nodes/block, 4 waves.
__global__ __launch_bounds__(256) void k_xw(const float* __restrict__ x, const unsigned short* __restrict__ Wt1b,
                                            const float* __restrict__ dis, unsigned short* __restrict__ y1b, int n) {
  __shared__ unsigned short Ws[NH * 136];
  __shared__ unsigned short xs[16 * 136];
  int t = threadIdx.x;
  int nodeBase = blockIdx.x * 16;
  for (int id = t; id < NH * 16; id += 256) {
    int c = id >> 4, kc = id & 15;
    *(short8*)&Ws[c * 136 + kc * 8] = *(const short8*)&Wt1b[c * NF + kc * 8];
  }
  {
    int nloc = t >> 4, kbase = (t & 15) * 8;
    int ebase = (nodeBase + nloc) * NF + kbase;
    const float4* xp = (const float4*)x;
    float4 a = xp[(ebase >> 2)];
    float4 b = xp[(ebase >> 2) + 1];
    float v[8] = {a.x, a.y, a.z, a.w, b.x, b.y, b.z, b.w};
#pragma unroll
    for (int q = 0; q < 8; ++q) {
      unsigned idx = (unsigned)(ebase + q);
      bool keep = (threefry_bits(idx) & 0x80000000u) == 0u;
      xs[nloc * 136 + kbase + q] = keep ? f2bf(v[q] * 2.0f) : 0;
    }
  }
  __syncthreads();
  int w = t >> 6, lane = t & 63;
  int m = lane & 15, quad = lane >> 4;
  float4v acc = {0.f, 0.f, 0.f, 0.f};
#pragma unroll
  for (int ks = 0; ks < 4; ++ks) {
    short8 a = *(const short8*)&xs[m * 136 + ks * 32 + quad * 8];
    short8 b = *(const short8*)&Ws[(w * 16 + m) * 136 + ks * 32 + quad * 8];
    acc = __builtin_amdgcn_mfma_f32_16x16x32_bf16(a, b, acc, 0, 0, 0);
  }
#pragma unroll
  for (int r = 0; r < 4; ++r) {
    int node = nodeBase + quad * 4 + r;
    y1b[node * NH + w * 16 + m] = f2bf(acc[r] * dis[node]);
  }
}

// g = bf16( dis[i] * relu( dis[i]*(sum y1[src] + y1[i]) + b1 ) ).  Wave/node, lane=feature.
__global__ __launch_bounds__(256) void k_agg1(const unsigned short* __restrict__ y1b, const int* __restrict__ rp,
                                              const int* __restrict__ csrc, const float* __restrict__ dis,
                                              const float* __restrict__ b1, unsigned short* __restrict__ gb, int n) {
  int i = blockIdx.x * 4 + (threadIdx.x >> 6);
  if (i >= n) return;
  int lane = threadIdx.x & 63;
  float acc = bf2f(y1b[i * NH + lane]);
  float a0 = 0.f, a1 = 0.f, a2 = 0.f, a3 = 0.f, a4 = 0.f, a5 = 0.f, a6 = 0.f, a7 = 0.f;
  int lo = rp[i], hi = rp[i + 1];
  for (int e0 = lo; e0 < hi; e0 += 64) {
    int e = e0 + lane;
    int sv = (e < hi) ? csrc[e] : 0;
    int cnt = hi - e0; if (cnt > 64) cnt = 64;
    int tt = 0;
    for (; tt + 8 <= cnt; tt += 8) {
      int s0 = __shfl(sv, tt + 0), s1 = __shfl(sv, tt + 1), s2 = __shfl(sv, tt + 2), s3 = __shfl(sv, tt + 3);
      int s4 = __shfl(sv, tt + 4), s5 = __shfl(sv, tt + 5), s6 = __shfl(sv, tt + 6), s7 = __shfl(sv, tt + 7);
      float v0 = bf2f(y1b[s0 * NH + lane]), v1 = bf2f(y1b[s1 * NH + lane]);
      float v2 = bf2f(y1b[s2 * NH + lane]), v3 = bf2f(y1b[s3 * NH + lane]);
      float v4 = bf2f(y1b[s4 * NH + lane]), v5 = bf2f(y1b[s5 * NH + lane]);
      float v6 = bf2f(y1b[s6 * NH + lane]), v7 = bf2f(y1b[s7 * NH + lane]);
      a0 += v0; a1 += v1; a2 += v2; a3 += v3; a4 += v4; a5 += v5; a6 += v6; a7 += v7;
    }
    for (; tt + 4 <= cnt; tt += 4) {
      int s0 = __shfl(sv, tt + 0), s1 = __shfl(sv, tt + 1), s2 = __shfl(sv, tt + 2), s3 = __shfl(sv, tt + 3);
      float v0 = bf2f(y1b[s0 * NH + lane]), v1 = bf2f(y1b[s1 * NH + lane]);
      float v2 = bf2f(y1b[s2 * NH + lane]), v3 = bf2f(y1b[s3 * NH + lane]);
      a0 += v0; a1 += v1; a2 += v2; a3 += v3;
    }
    for (; tt < cnt; ++tt) {
      int s = __shfl(sv, tt);
      acc += bf2f(y1b[s * NH + lane]);
    }
  }
  acc += ((a0 + a1) + (a2 + a3)) + ((a4 + a5) + (a6 + a7));
  float di = dis[i];
  float hval = fmaxf(fmaf(di, acc, b1[lane]), 0.f);
  gb[i * NH + lane] = f2bf(di * hval);
}

// ah = bf16( dis[i] * (sum g[src] + g[i]) ).  Identical gather structure, 64 aligned lanes.
__global__ __launch_bounds__(256) void k_aggg(const unsigned short* __restrict__ gb, const int* __restrict__ rp,
                                              const int* __restrict__ csrc, const float* __restrict__ dis,
                                              unsigned short* __restrict__ ahb, int n) {
  int i = blockIdx.x * 4 + (threadIdx.x >> 6);
  if (i >= n) return;
  int lane = threadIdx.x & 63;
  float acc = bf2f(gb[i * NH + lane]);
  float a0 = 0.f, a1 = 0.f, a2 = 0.f, a3 = 0.f, a4 = 0.f, a5 = 0.f, a6 = 0.f, a7 = 0.f;
  int lo = rp[i], hi = rp[i + 1];
  for (int e0 = lo; e0 < hi; e0 += 64) {
    int e = e0 + lane;
    int sv = (e < hi) ? csrc[e] : 0;
    int cnt = hi - e0; if (cnt > 64) cnt = 64;
    int tt = 0;
    for (; tt + 8 <= cnt; tt += 8) {
      int s0 = __shfl(sv, tt + 0), s1 = __shfl(sv, tt + 1), s2 = __shfl(sv, tt + 2), s3 = __shfl(sv, tt + 3);
      int s4 = __shfl(sv, tt + 4), s5 = __shfl(sv, tt + 5), s6 = __shfl(sv, tt + 6), s7 = __shfl(sv, tt + 7);
      float v0 = bf2f(gb[s0 * NH + lane]), v1 = bf2f(gb[s1 * NH + lane]);
      float v2 = bf2f(gb[s2 * NH + lane]), v3 = bf2f(gb[s3 * NH + lane]);
      float v4 = bf2f(gb[s4 * NH + lane]), v5 = bf2f(gb[s5 * NH + lane]);
      float v6 = bf2f(gb[s6 * NH + lane]), v7 = bf2f(gb[s7 * NH + lane]);
      a0 += v0; a1 += v1; a2 += v2; a3 += v3; a4 += v4; a5 += v5; a6 += v6; a7 += v7;
    }
    for (; tt + 4 <= cnt; tt += 4) {
      int s0 = __shfl(sv, tt + 0), s1 = __shfl(sv, tt + 1), s2 = __shfl(sv, tt + 2), s3 = __shfl(sv, tt + 3);
      float v0 = bf2f(gb[s0 * NH + lane]), v1 = bf2f(gb[s1 * NH + lane]);
      float v2 = bf2f(gb[s2 * NH + lane]), v3 = bf2f(gb[s3 * NH + lane]);
      a0 += v0; a1 += v1; a2 += v2; a3 += v3;
    }
    for (; tt < cnt; ++tt) {
      int s = __shfl(sv, tt);
      acc += bf2f(gb[s * NH + lane]);
    }
  }
  acc += ((a0 + a1) + (a2 + a3)) + ((a4 + a5) + (a6 + a7));
  ahb[i * NH + lane] = f2bf(dis[i] * acc);
}

// out = ah @ W2 + b2  (fp32 out, direct).  16 nodes/block, 3 waves (48 padded cols).
__global__ __launch_bounds__(192) void k_hw2(const unsigned short* __restrict__ ahb, const unsigned short* __restrict__ Wt2b,
                                             const float* __restrict__ b2, float* __restrict__ out, int n) {
  __shared__ unsigned short Ws[48 * 72];
  __shared__ unsigned short xs[16 * 72];
  int t = threadIdx.x;
  int nodeBase = blockIdx.x * 16;
  for (int id = t; id < 48 * 8; id += 192) {
    int c = id >> 3, kc = id & 7;
    *(short8*)&Ws[c * 72 + kc * 8] = *(const short8*)&Wt2b[c * NH + kc * 8];
  }
  if (t < 128) {
    int c = t >> 3, kc = t & 7;
    *(short8*)&xs[c * 72 + kc * 8] = *(const short8*)&ahb[(nodeBase + c) * NH + kc * 8];
  }
  __syncthreads();
  int w = t >> 6, lane = t & 63;
  int m = lane & 15, quad = lane >> 4;
  float4v acc = {0.f, 0.f, 0.f, 0.f};
#pragma unroll
  for (int ks = 0; ks < 2; ++ks) {
    short8 a = *(const short8*)&xs[m * 72 + ks * 32 + quad * 8];
    short8 b = *(const short8*)&Ws[(w * 16 + m) * 72 + ks * 32 + quad * 8];
    acc = __builtin_amdgcn_mfma_f32_16x16x32_bf16(a, b, acc, 0, 0, 0);
  }
  int col = w * 16 + m;
  if (col < NC) {
    float bias = b2[col];
#pragma unroll
    for (int r = 0; r < 4; ++r) {
      int node = nodeBase + quad * 4 + r;
      out[node * NC + col] = acc[r] + bias;
    }
  }
}

extern "C" void kernel_launch(void* const* d_in, const int* in_sizes, int n_in,
                              void* d_out, int out_size, void* d_ws, size_t ws_size,
                              hipStream_t stream) {
  const float* x  = (const float*)d_in[0];
  const int*   ei = (const int*)d_in[1];
  const float* W1 = (const float*)d_in[2];
  const float* b1 = (const float*)d_in[3];
  const float* W2 = (const float*)d_in[4];
  const float* b2 = (const float*)d_in[5];
  float* out = (float*)d_out;
  int n  = in_sizes[0] / NF;    // 100000
  int nE = in_sizes[1] / 2;     // 1600000
  const int* src = ei;
  const int* dst = ei + nE;

  char* ws = (char*)d_ws;
  float* dis   = (float*)(ws + 0);                    // 400 KB
  int*   rp    = (int*)(ws + 400000);                 // n+1 ints
  int*   bcnt  = (int*)(ws + 800128);
  int*   bbase = (int*)(ws + 800640);
  int*   gcur  = (int*)(ws + 801152);
  unsigned short* Wt1b = (unsigned short*)(ws + 801664);   // 16 KB
  unsigned short* Wt2b = (unsigned short*)(ws + 818048);   // 6 KB
  int*   csrc  = (int*)(ws + 824192);                 // 6.4 MB
  unsigned short* y1b = (unsigned short*)(ws + 7224192);   // 12.8 MB (reused as ahb)
  unsigned short* gb  = (unsigned short*)(ws + 20024192);  // 12.8 MB
  unsigned* binned = (unsigned*)(ws + 20024192);      // 6.4 MB, overlays gb (dead before agg1)
  unsigned short* ahb = y1b;                          // y1 dead after agg1

  hipMemsetAsync(bcnt, 0, NB * 4, stream);

  k_prep <<<(NF * NH + 48 * NH + 255) / 256, 256, 0, stream>>>(W1, W2, Wt1b, Wt2b);
  k_bhist<<<512, 256, 0, stream>>>(dst, bcnt, nE);
  k_bscan<<<1, 128, 0, stream>>>(bcnt, bbase, gcur, rp, n, nE);
  k_bin  <<<(nE + BIN_T - 1) / BIN_T, 256, 0, stream>>>(src, dst, gcur, binned, nE);
  k_fillb<<<NB, 1024, 0, stream>>>(binned, bbase, rp, dis, csrc, n);
  k_xw   <<<n / 16, 256, 0, stream>>>(x, Wt1b, dis, y1b, n);
  k_agg1 <<<(n + 3) / 4, 256, 0, stream>>>(y1b, rp, csrc, dis, b1, gb, n);
  k_aggg <<<(n + 3) / 4, 256, 0, stream>>>(gb, rp, csrc, dis, ahb, n);
  k_hw2  <<<n / 16, 192, 0, stream>>>(ahb, Wt2b, b2, out, n);
}